// Round 3
// baseline (4818.881 us; speedup 1.0000x reference)
//
#include <hip/hip_runtime.h>
#include <hip/hip_bf16.h>
#include <math.h>

#define TT 128
#define NN 64
#define HH 1024
#define AA 16
#define G3 3072          /* 3*HH */
#define NC 6144          /* combined gi cols */
#define PK 1088          /* padded policy K (1040 -> 1088 = 17*64), zero tail */
#define WLDS_STRIDE 1032 /* LDS stride for persistent weight tile */
#define NBLK 128         /* persistent grid */

#define PD_OFF  0
#define POL_OFF (TT*NN*AA)                  /* 131072 */
#define HXS_OFF (POL_OFF + TT*NN*HH)        /* 8519680 */

typedef __attribute__((ext_vector_type(8))) short short8;
typedef __attribute__((ext_vector_type(4))) float f32x4;

// ---- persistent device buffers (fully rewritten every call) ----
__device__ __align__(16) __hip_bfloat16 g_c_bf[TT*NN*HH];
__device__ __align__(16) __hip_bfloat16 g_wihc_bf[NC*HH];
__device__ __align__(16) __hip_bfloat16 g_whh_bf[2][G3*HH];
__device__ __align__(16) __hip_bfloat16 g_pw1_bf[HH*PK];
__device__ __align__(16) __hip_bfloat16 g_pw2_bf[AA*HH];
__device__ float g_gi[(size_t)TT*NN*NC];                        // 201 MB fp32
__device__ float g_h[NN*HH];
__device__ float g_pol[NN*HH];
__device__ __align__(16) __hip_bfloat16 g_pin_all[(TT+1)*NN*PK]; // [h(t-1)*m_t | a_t*m_t | 0]
__device__ __align__(16) __hip_bfloat16 g_polm[2][NN*HH];
__device__ __align__(16) __hip_bfloat16 g_ph_all[TT*NN*HH];      // tanh(policy hidden), bf16
__device__ unsigned int g_bar_count;
__device__ unsigned int g_bar_epoch;

__device__ __forceinline__ float sigmoidf_(float x) { return 1.0f / (1.0f + __expf(-x)); }
__device__ __forceinline__ float tanhf_(float x) {
  float e = __expf(2.0f * x);
  return 1.0f - 2.0f / (e + 1.0f);
}

// ---------------- conversions ----------------
__global__ __launch_bounds__(256) void conv_all(
    const float* __restrict__ c, const float* __restrict__ masks, const float* __restrict__ act,
    const float* __restrict__ wih_h, const float* __restrict__ wih_p,
    const float* __restrict__ whh_h, const float* __restrict__ whh_p,
    const float* __restrict__ pw1, const float* __restrict__ pw2)
{
  size_t i = (size_t)blockIdx.x * 256 + threadIdx.x;
  size_t stride = (size_t)gridDim.x * 256;
  for (size_t f = i; f < (size_t)TT*NN*HH; f += stride) g_c_bf[f] = __float2bfloat16(c[f]);
  for (size_t f = i; f < (size_t)G3*HH; f += stride) {
    g_wihc_bf[f]                 = __float2bfloat16(wih_h[f]);
    g_wihc_bf[(size_t)G3*HH + f] = __float2bfloat16(wih_p[f]);
    g_whh_bf[0][f] = __float2bfloat16(whh_h[f]);
    g_whh_bf[1][f] = __float2bfloat16(whh_p[f]);
  }
  for (size_t f = i; f < (size_t)HH*PK; f += stride) {
    int o = (int)(f / PK), j = (int)(f % PK);
    g_pw1_bf[f] = (j < HH + AA) ? __float2bfloat16(pw1[(size_t)o*(HH+AA) + j]) : __float2bfloat16(0.0f);
  }
  for (size_t f = i; f < (size_t)AA*HH; f += stride) g_pw2_bf[f] = __float2bfloat16(pw2[f]);
  // action columns + pad of pin_all, for all t
  for (size_t f = i; f < (size_t)TT*NN*(PK-HH); f += stride) {
    int row = (int)(f >> 6), j = (int)(f & 63);          // row = t*NN+n
    float v = (j < AA) ? act[(size_t)row*AA + j] * masks[row] : 0.0f;
    g_pin_all[(size_t)row*PK + HH + j] = __float2bfloat16(v);
  }
}

__global__ __launch_bounds__(256) void init_kernel(const float* __restrict__ hxs,
                                                   const float* __restrict__ masks) {
  int f = blockIdx.x * 256 + threadIdx.x;      // NN*HH threads
  int n = f >> 10, j = f & 1023;
  float m0 = masks[n];
  float hv = hxs[n * 2 * HH + j];
  float pv = hxs[n * 2 * HH + HH + j];
  g_h[f] = hv;
  g_pol[f] = pv;
  g_pin_all[(size_t)n * PK + j] = __float2bfloat16(hv * m0);
  g_polm[0][n * HH + j]         = __float2bfloat16(pv * m0);
  if (f == 0) { g_bar_count = 0; g_bar_epoch = 0; }
}

// ---------------- pre_gemm: gi = c @ [wih_h;wih_p].T   128x128 tile, BK=64, dbuf ----------------
__global__ __launch_bounds__(256) void pre_gemm() {
  __shared__ __align__(16) __hip_bfloat16 As[2][128 * 72];
  __shared__ __align__(16) __hip_bfloat16 Bs[2][128 * 72];
  const int tid = threadIdx.x, l = tid & 63, w = tid >> 6;
  const int bm = blockIdx.x / 48, bn = blockIdx.x % 48;
  const __hip_bfloat16* A = g_c_bf    + (size_t)bm * 128 * HH;
  const __hip_bfloat16* B = g_wihc_bf + (size_t)bn * 128 * HH;
  const int roff = (w >> 1) * 64, coff = (w & 1) * 64;

  short8 ra[4], rb[4];
#define PG_LOAD(KT) { _Pragma("unroll") for (int q = 0; q < 4; ++q) { \
    int cch = q * 256 + tid; int row = cch >> 3, ko = (cch & 7) * 8; \
    ra[q] = *(const short8*)(A + (size_t)row * HH + (KT) * 64 + ko); \
    rb[q] = *(const short8*)(B + (size_t)row * HH + (KT) * 64 + ko); } }
#define PG_STORE(BUF) { _Pragma("unroll") for (int q = 0; q < 4; ++q) { \
    int cch = q * 256 + tid; int row = cch >> 3, ko = (cch & 7) * 8; \
    *(short8*)(&As[BUF][row * 72 + ko]) = ra[q]; \
    *(short8*)(&Bs[BUF][row * 72 + ko]) = rb[q]; } }

  PG_LOAD(0); PG_STORE(0);
  f32x4 acc[4][4] = {};
  for (int kt = 0; kt < 16; ++kt) {
    __syncthreads();
    if (kt < 15) PG_LOAD(kt + 1);
    const int buf = kt & 1;
#pragma unroll
    for (int ks = 0; ks < 2; ++ks) {
      short8 a[4], b[4];
#pragma unroll
      for (int fr = 0; fr < 4; ++fr)
        a[fr] = *(const short8*)(&As[buf][(roff + fr * 16 + (l & 15)) * 72 + ks * 32 + (l >> 4) * 8]);
#pragma unroll
      for (int fc = 0; fc < 4; ++fc)
        b[fc] = *(const short8*)(&Bs[buf][(coff + fc * 16 + (l & 15)) * 72 + ks * 32 + (l >> 4) * 8]);
#pragma unroll
      for (int fr = 0; fr < 4; ++fr)
#pragma unroll
        for (int fc = 0; fc < 4; ++fc)
          acc[fr][fc] = __builtin_amdgcn_mfma_f32_16x16x32_bf16(a[fr], b[fc], acc[fr][fc], 0, 0, 0);
    }
    if (kt < 15) PG_STORE((kt + 1) & 1);
  }
#pragma unroll
  for (int fr = 0; fr < 4; ++fr)
#pragma unroll
    for (int fc = 0; fc < 4; ++fc)
#pragma unroll
      for (int reg = 0; reg < 4; ++reg) {
        int row = bm * 128 + roff + fr * 16 + (l >> 4) * 4 + reg;
        int col = bn * 128 + coff + fc * 16 + (l & 15);
        g_gi[(size_t)row * NC + col] = acc[fr][fc][reg];
      }
}

// ---------------- persistent 2-GRU scan kernel ----------------
// 128 blocks: 0..63 GRU-h (cols b*16), 64..127 GRU-pol. Weights in LDS once.
__global__ __launch_bounds__(256) void step_persist(
    const float* __restrict__ masks,
    const float* __restrict__ bih_h, const float* __restrict__ bhh_h,
    const float* __restrict__ bih_p, const float* __restrict__ bhh_p,
    float* __restrict__ out)
{
  extern __shared__ __align__(16) __hip_bfloat16 Ws[];   // [48][WLDS_STRIDE]
  const int tid = threadIdx.x, l = tid & 63, w = tid >> 6;
  const int gru = blockIdx.x >> 6;
  const int c0  = (blockIdx.x & 63) * 16;
  const __hip_bfloat16* __restrict__ W = g_whh_bf[gru];

  // one-time weight staging: rows = gate*16 + j  (weight row gate*HH + c0 + j), K=1024
  for (int ch = tid; ch < 48 * 128; ch += 256) {
    int row = ch >> 7, ko = (ch & 127) * 8;
    int gate = row >> 4, j = row & 15;
    *(short8*)(&Ws[row * WLDS_STRIDE + ko]) =
        *(const short8*)(W + (size_t)(gate * HH + c0 + j) * HH + ko);
  }
  __syncthreads();

  const float* bi = (gru == 0) ? bih_h : bih_p;
  const float* bh = (gru == 0) ? bhh_h : bhh_p;
  float* st = (gru == 0) ? g_h : g_pol;
  const int col = c0 + (l & 15);
  const float bir = bi[col],        bhr = bh[col];
  const float biz = bi[HH + col],   bhz = bh[HH + col];
  const float bin = bi[2*HH + col], bhn = bh[2*HH + col];
  const int rowbase = w * 16 + (l >> 4) * 4;
  const int arow = w * 16 + (l & 15);

  for (int t = 0; t < TT; ++t) {
    const __hip_bfloat16* __restrict__ Ab =
        (gru == 0) ? (g_pin_all + (size_t)t * NN * PK) : g_polm[t & 1];
    const int astr = (gru == 0) ? PK : HH;

    // prefetch epilogue operands (HBM gi hidden under MFMA loop)
    float gi_r[4], gi_z[4], gi_n[4], hprev[4], mk[4], mk1[4];
#pragma unroll
    for (int reg = 0; reg < 4; ++reg) {
      int row = rowbase + reg;
      mk[reg]  = masks[t * NN + row];
      mk1[reg] = (t < TT - 1) ? masks[(t + 1) * NN + row] : 1.0f;
      const float* gp = g_gi + (size_t)(t * NN + row) * NC + gru * G3 + col;
      gi_r[reg] = gp[0];
      gi_z[reg] = gp[HH];
      gi_n[reg] = gp[2 * HH];
      hprev[reg] = st[row * HH + col];
    }

    f32x4 acc0 = {}, acc1 = {}, acc2 = {};
#pragma unroll 4
    for (int k32 = 0; k32 < 32; ++k32) {
      short8 a = *(const short8*)(Ab + (size_t)arow * astr + k32 * 32 + (l >> 4) * 8);
      short8 b0 = *(const short8*)(&Ws[( 0 + (l & 15)) * WLDS_STRIDE + k32 * 32 + (l >> 4) * 8]);
      short8 b1 = *(const short8*)(&Ws[(16 + (l & 15)) * WLDS_STRIDE + k32 * 32 + (l >> 4) * 8]);
      short8 b2 = *(const short8*)(&Ws[(32 + (l & 15)) * WLDS_STRIDE + k32 * 32 + (l >> 4) * 8]);
      acc0 = __builtin_amdgcn_mfma_f32_16x16x32_bf16(a, b0, acc0, 0, 0, 0);
      acc1 = __builtin_amdgcn_mfma_f32_16x16x32_bf16(a, b1, acc1, 0, 0, 0);
      acc2 = __builtin_amdgcn_mfma_f32_16x16x32_bf16(a, b2, acc2, 0, 0, 0);
    }

#pragma unroll
    for (int reg = 0; reg < 4; ++reg) {
      int row = rowbase + reg;
      float hm = hprev[reg] * mk[reg];
      float rg  = sigmoidf_(gi_r[reg] + acc0[reg] + bir + bhr);
      float z   = sigmoidf_(gi_z[reg] + acc1[reg] + biz + bhz);
      float nn2 = tanhf_  (gi_n[reg] + bin + rg * (acc2[reg] + bhn));
      float hv = (1.0f - z) * nn2 + z * hm;
      st[row * HH + col] = hv;
      if (gru == 0) {
        g_pin_all[(size_t)(t + 1) * NN * PK + (size_t)row * PK + col] = __float2bfloat16(hv * mk1[reg]);
      } else {
        g_polm[(t + 1) & 1][row * HH + col] = __float2bfloat16(hv * mk1[reg]);
        out[POL_OFF + (size_t)(t * NN + row) * HH + col] = hv;
      }
    }

    // ---- grid barrier (epoch t+1) ----
    __threadfence();
    __syncthreads();
    if (tid == 0) {
      if (__hip_atomic_fetch_add(&g_bar_count, 1u, __ATOMIC_ACQ_REL, __HIP_MEMORY_SCOPE_AGENT) == NBLK - 1) {
        __hip_atomic_store(&g_bar_count, 0u, __ATOMIC_RELAXED, __HIP_MEMORY_SCOPE_AGENT);
        __hip_atomic_store(&g_bar_epoch, (unsigned)(t + 1), __ATOMIC_RELEASE, __HIP_MEMORY_SCOPE_AGENT);
      } else {
        while (__hip_atomic_load(&g_bar_epoch, __ATOMIC_RELAXED, __HIP_MEMORY_SCOPE_AGENT) < (unsigned)(t + 1))
          __builtin_amdgcn_s_sleep(1);
      }
    }
    __syncthreads();
    __threadfence();
  }
}

// ---------------- post: ph_all = tanh(pin_all @ pw1.T + b1)   128x128 tile ----------------
__global__ __launch_bounds__(256) void pol_gemm(const float* __restrict__ pb1) {
  __shared__ __align__(16) __hip_bfloat16 As[2][128 * 72];
  __shared__ __align__(16) __hip_bfloat16 Bs[2][128 * 72];
  const int tid = threadIdx.x, l = tid & 63, w = tid >> 6;
  const int bm = blockIdx.x / 8, bn = blockIdx.x % 8;
  const __hip_bfloat16* A = g_pin_all + (size_t)bm * 128 * PK;
  const __hip_bfloat16* B = g_pw1_bf  + (size_t)bn * 128 * PK;
  const int roff = (w >> 1) * 64, coff = (w & 1) * 64;

  short8 ra[4], rb[4];
#define PL_LOAD(KT) { _Pragma("unroll") for (int q = 0; q < 4; ++q) { \
    int cch = q * 256 + tid; int row = cch >> 3, ko = (cch & 7) * 8; \
    ra[q] = *(const short8*)(A + (size_t)row * PK + (KT) * 64 + ko); \
    rb[q] = *(const short8*)(B + (size_t)row * PK + (KT) * 64 + ko); } }
#define PL_STORE(BUF) { _Pragma("unroll") for (int q = 0; q < 4; ++q) { \
    int cch = q * 256 + tid; int row = cch >> 3, ko = (cch & 7) * 8; \
    *(short8*)(&As[BUF][row * 72 + ko]) = ra[q]; \
    *(short8*)(&Bs[BUF][row * 72 + ko]) = rb[q]; } }

  PL_LOAD(0); PL_STORE(0);
  f32x4 acc[4][4] = {};
  for (int kt = 0; kt < 17; ++kt) {
    __syncthreads();
    if (kt < 16) PL_LOAD(kt + 1);
    const int buf = kt & 1;
#pragma unroll
    for (int ks = 0; ks < 2; ++ks) {
      short8 a[4], b[4];
#pragma unroll
      for (int fr = 0; fr < 4; ++fr)
        a[fr] = *(const short8*)(&As[buf][(roff + fr * 16 + (l & 15)) * 72 + ks * 32 + (l >> 4) * 8]);
#pragma unroll
      for (int fc = 0; fc < 4; ++fc)
        b[fc] = *(const short8*)(&Bs[buf][(coff + fc * 16 + (l & 15)) * 72 + ks * 32 + (l >> 4) * 8]);
#pragma unroll
      for (int fr = 0; fr < 4; ++fr)
#pragma unroll
        for (int fc = 0; fc < 4; ++fc)
          acc[fr][fc] = __builtin_amdgcn_mfma_f32_16x16x32_bf16(a[fr], b[fc], acc[fr][fc], 0, 0, 0);
    }
    if (kt < 16) PL_STORE((kt + 1) & 1);
  }
#pragma unroll
  for (int fc = 0; fc < 4; ++fc) {
    int col = bn * 128 + coff + fc * 16 + (l & 15);
    float b1v = pb1[col];
#pragma unroll
    for (int fr = 0; fr < 4; ++fr)
#pragma unroll
      for (int reg = 0; reg < 4; ++reg) {
        int row = bm * 128 + roff + fr * 16 + (l >> 4) * 4 + reg;
        g_ph_all[(size_t)row * HH + col] = __float2bfloat16(tanhf_(acc[fr][fc][reg] + b1v));
      }
  }
}

// ---------------- post: pdist = ph_all @ pw2.T + b2 ----------------
__global__ __launch_bounds__(256) void pdist_kernel(const float* __restrict__ pb2,
                                                    float* __restrict__ out) {
  const int tid = threadIdx.x, l = tid & 63, w = tid >> 6;
  const int r0 = blockIdx.x * 64;
  f32x4 pa = {};
  const __hip_bfloat16* PH = g_ph_all + (size_t)(r0 + w * 16 + (l & 15)) * HH;
  const __hip_bfloat16* B  = g_pw2_bf + (size_t)(l & 15) * HH;
#pragma unroll 4
  for (int k32 = 0; k32 < 32; ++k32) {
    short8 a = *(const short8*)(PH + k32 * 32 + (l >> 4) * 8);
    short8 b = *(const short8*)(B  + k32 * 32 + (l >> 4) * 8);
    pa = __builtin_amdgcn_mfma_f32_16x16x32_bf16(a, b, pa, 0, 0, 0);
  }
  int o = l & 15;
  float bb = pb2[o];
#pragma unroll
  for (int reg = 0; reg < 4; ++reg) {
    int row = r0 + w * 16 + (l >> 4) * 4 + reg;
    out[PD_OFF + (size_t)row * AA + o] = pa[reg] + bb;
  }
}

// ---------------- final: hxs output ----------------
__global__ __launch_bounds__(256) void final_kernel(float* __restrict__ out) {
  int f = blockIdx.x * 256 + threadIdx.x;   // < 131072
  int n = f >> 11, j = f & 2047;
  out[HXS_OFF + f] = (j < HH) ? g_h[n * HH + j] : g_pol[n * HH + (j - HH)];
}

extern "C" void kernel_launch(void* const* d_in, const int* in_sizes, int n_in,
                              void* d_out, int out_size, void* d_ws, size_t ws_size,
                              hipStream_t stream) {
  const float* c     = (const float*)d_in[0];
  const float* hxs   = (const float*)d_in[1];
  const float* masks = (const float*)d_in[2];
  const float* act   = (const float*)d_in[3];
  const float* wih_h = (const float*)d_in[4];
  const float* whh_h = (const float*)d_in[5];
  const float* bih_h = (const float*)d_in[6];
  const float* bhh_h = (const float*)d_in[7];
  const float* wih_p = (const float*)d_in[8];
  const float* whh_p = (const float*)d_in[9];
  const float* bih_p = (const float*)d_in[10];
  const float* bhh_p = (const float*)d_in[11];
  const float* pw1   = (const float*)d_in[12];
  const float* pb1   = (const float*)d_in[13];
  const float* pw2   = (const float*)d_in[14];
  const float* pb2   = (const float*)d_in[15];
  float* out = (float*)d_out;

  static int lds_set = 0;
  const int wlds_bytes = 48 * WLDS_STRIDE * 2;   // 99072
  hipFuncSetAttribute((const void*)step_persist,
                      hipFuncAttributeMaxDynamicSharedMemorySize, wlds_bytes);

  conv_all<<<4096, 256, 0, stream>>>(c, masks, act, wih_h, wih_p, whh_h, whh_p, pw1, pw2);
  init_kernel<<<256, 256, 0, stream>>>(hxs, masks);
  pre_gemm<<<3072, 256, 0, stream>>>();
  step_persist<<<NBLK, 256, wlds_bytes, stream>>>(masks, bih_h, bhh_h, bih_p, bhh_p, out);
  pol_gemm<<<512, 256, 0, stream>>>(pb1);
  pdist_kernel<<<128, 256, 0, stream>>>(pb2, out);
  final_kernel<<<512, 256, 0, stream>>>(out);
}

// Round 4
// 2707.335 us; speedup vs baseline: 1.7799x; 1.7799x over previous
//
#include <hip/hip_runtime.h>
#include <hip/hip_bf16.h>
#include <math.h>

#define TT 128
#define NN 64
#define HH 1024
#define AA 16
#define G3 3072          /* 3*HH */
#define NC 6144          /* combined gi cols */
#define PK 1088          /* padded policy K (1040 -> 1088 = 17*64), zero tail */
#define WLDS_STRIDE 1032 /* LDS stride for persistent weight tile */
#define NBLK 128         /* persistent grid */

#define PD_OFF  0
#define POL_OFF (TT*NN*AA)                  /* 131072 */
#define HXS_OFF (POL_OFF + TT*NN*HH)        /* 8519680 */

typedef __attribute__((ext_vector_type(8))) short short8;
typedef __attribute__((ext_vector_type(4))) float f32x4;

// ---- persistent device buffers (fully rewritten every call) ----
__device__ __align__(16) __hip_bfloat16 g_c_bf[TT*NN*HH];
__device__ __align__(16) __hip_bfloat16 g_wihc_bf[NC*HH];
__device__ __align__(16) __hip_bfloat16 g_whh_bf[2][G3*HH];
__device__ __align__(16) __hip_bfloat16 g_pw1_bf[HH*PK];
__device__ __align__(16) __hip_bfloat16 g_pw2_bf[AA*HH];
__device__ float g_gi[(size_t)TT*NN*NC];                        // 201 MB fp32
__device__ float g_h[NN*HH];
__device__ float g_pol[NN*HH];
__device__ __align__(16) __hip_bfloat16 g_pin_all[(TT+1)*NN*PK]; // [h(t-1)*m_t | a_t*m_t | 0]
__device__ __align__(16) __hip_bfloat16 g_polm[2][NN*HH];
__device__ __align__(16) __hip_bfloat16 g_ph_all[TT*NN*HH];      // tanh(policy hidden), bf16

struct BarFlag { unsigned v; unsigned pad[31]; };                 // 128B per flag
__device__ BarFlag g_flags[2][64];

__device__ __forceinline__ float sigmoidf_(float x) { return 1.0f / (1.0f + __expf(-x)); }
__device__ __forceinline__ float tanhf_(float x) {
  float e = __expf(2.0f * x);
  return 1.0f - 2.0f / (e + 1.0f);
}

// ---------------- conversions ----------------
__global__ __launch_bounds__(256) void conv_all(
    const float* __restrict__ c, const float* __restrict__ masks, const float* __restrict__ act,
    const float* __restrict__ wih_h, const float* __restrict__ wih_p,
    const float* __restrict__ whh_h, const float* __restrict__ whh_p,
    const float* __restrict__ pw1, const float* __restrict__ pw2)
{
  size_t i = (size_t)blockIdx.x * 256 + threadIdx.x;
  size_t stride = (size_t)gridDim.x * 256;
  for (size_t f = i; f < (size_t)TT*NN*HH; f += stride) g_c_bf[f] = __float2bfloat16(c[f]);
  for (size_t f = i; f < (size_t)G3*HH; f += stride) {
    g_wihc_bf[f]                 = __float2bfloat16(wih_h[f]);
    g_wihc_bf[(size_t)G3*HH + f] = __float2bfloat16(wih_p[f]);
    g_whh_bf[0][f] = __float2bfloat16(whh_h[f]);
    g_whh_bf[1][f] = __float2bfloat16(whh_p[f]);
  }
  for (size_t f = i; f < (size_t)HH*PK; f += stride) {
    int o = (int)(f / PK), j = (int)(f % PK);
    g_pw1_bf[f] = (j < HH + AA) ? __float2bfloat16(pw1[(size_t)o*(HH+AA) + j]) : __float2bfloat16(0.0f);
  }
  for (size_t f = i; f < (size_t)AA*HH; f += stride) g_pw2_bf[f] = __float2bfloat16(pw2[f]);
  for (size_t f = i; f < (size_t)TT*NN*(PK-HH); f += stride) {
    int row = (int)(f >> 6), j = (int)(f & 63);
    float v = (j < AA) ? act[(size_t)row*AA + j] * masks[row] : 0.0f;
    g_pin_all[(size_t)row*PK + HH + j] = __float2bfloat16(v);
  }
}

__global__ __launch_bounds__(256) void init_kernel(const float* __restrict__ hxs,
                                                   const float* __restrict__ masks) {
  int f = blockIdx.x * 256 + threadIdx.x;      // NN*HH threads
  int n = f >> 10, j = f & 1023;
  float m0 = masks[n];
  float hv = hxs[n * 2 * HH + j];
  float pv = hxs[n * 2 * HH + HH + j];
  g_h[f] = hv;
  g_pol[f] = pv;
  g_pin_all[(size_t)n * PK + j] = __float2bfloat16(hv * m0);
  g_polm[0][n * HH + j]         = __float2bfloat16(pv * m0);
  if (f < 128) g_flags[f >> 6][f & 63].v = 0u;
}

// ---------------- pre_gemm: gi = c @ [wih_h;wih_p].T   128x128 tile, BK=64, dbuf ----------------
__global__ __launch_bounds__(256) void pre_gemm() {
  __shared__ __align__(16) __hip_bfloat16 As[2][128 * 72];
  __shared__ __align__(16) __hip_bfloat16 Bs[2][128 * 72];
  const int tid = threadIdx.x, l = tid & 63, w = tid >> 6;
  const int bm = blockIdx.x / 48, bn = blockIdx.x % 48;
  const __hip_bfloat16* A = g_c_bf    + (size_t)bm * 128 * HH;
  const __hip_bfloat16* B = g_wihc_bf + (size_t)bn * 128 * HH;
  const int roff = (w >> 1) * 64, coff = (w & 1) * 64;

  short8 ra[4], rb[4];
#define PG_LOAD(KT) { _Pragma("unroll") for (int q = 0; q < 4; ++q) { \
    int cch = q * 256 + tid; int row = cch >> 3, ko = (cch & 7) * 8; \
    ra[q] = *(const short8*)(A + (size_t)row * HH + (KT) * 64 + ko); \
    rb[q] = *(const short8*)(B + (size_t)row * HH + (KT) * 64 + ko); } }
#define PG_STORE(BUF) { _Pragma("unroll") for (int q = 0; q < 4; ++q) { \
    int cch = q * 256 + tid; int row = cch >> 3, ko = (cch & 7) * 8; \
    *(short8*)(&As[BUF][row * 72 + ko]) = ra[q]; \
    *(short8*)(&Bs[BUF][row * 72 + ko]) = rb[q]; } }

  PG_LOAD(0); PG_STORE(0);
  f32x4 acc[4][4] = {};
  for (int kt = 0; kt < 16; ++kt) {
    __syncthreads();
    if (kt < 15) PG_LOAD(kt + 1);
    const int buf = kt & 1;
#pragma unroll
    for (int ks = 0; ks < 2; ++ks) {
      short8 a[4], b[4];
#pragma unroll
      for (int fr = 0; fr < 4; ++fr)
        a[fr] = *(const short8*)(&As[buf][(roff + fr * 16 + (l & 15)) * 72 + ks * 32 + (l >> 4) * 8]);
#pragma unroll
      for (int fc = 0; fc < 4; ++fc)
        b[fc] = *(const short8*)(&Bs[buf][(coff + fc * 16 + (l & 15)) * 72 + ks * 32 + (l >> 4) * 8]);
#pragma unroll
      for (int fr = 0; fr < 4; ++fr)
#pragma unroll
        for (int fc = 0; fc < 4; ++fc)
          acc[fr][fc] = __builtin_amdgcn_mfma_f32_16x16x32_bf16(a[fr], b[fc], acc[fr][fc], 0, 0, 0);
    }
    if (kt < 15) PG_STORE((kt + 1) & 1);
  }
#pragma unroll
  for (int fr = 0; fr < 4; ++fr)
#pragma unroll
    for (int fc = 0; fc < 4; ++fc)
#pragma unroll
      for (int reg = 0; reg < 4; ++reg) {
        int row = bm * 128 + roff + fr * 16 + (l >> 4) * 4 + reg;
        int col = bn * 128 + coff + fc * 16 + (l & 15);
        g_gi[(size_t)row * NC + col] = acc[fr][fc][reg];
      }
}

// ---------------- persistent 2-GRU scan kernel ----------------
// 128 blocks: 0..63 GRU-h (cols idx*16), 64..127 GRU-pol. Independent barrier per GRU group.
__global__ __launch_bounds__(256) void step_persist(
    const float* __restrict__ masks,
    const float* __restrict__ bih_h, const float* __restrict__ bhh_h,
    const float* __restrict__ bih_p, const float* __restrict__ bhh_p,
    float* __restrict__ out)
{
  extern __shared__ __align__(16) __hip_bfloat16 Ws[];   // [48][WLDS_STRIDE]
  __shared__ float m_lds[TT * NN];                       // 32 KB masks
  const int tid = threadIdx.x, l = tid & 63, w = tid >> 6;
  const int gru = blockIdx.x >> 6;
  const int idx = blockIdx.x & 63;
  const int c0  = idx * 16;
  const __hip_bfloat16* __restrict__ W = g_whh_bf[gru];

  for (int i = tid; i < TT * NN; i += 256) m_lds[i] = masks[i];

  // one-time weight staging: LDS row = gate*16 + j  <=  weight row gate*HH + c0 + j
  for (int ch = tid; ch < 48 * 128; ch += 256) {
    int row = ch >> 7, ko = (ch & 127) * 8;
    int gate = row >> 4, j = row & 15;
    *(short8*)(&Ws[row * WLDS_STRIDE + ko]) =
        *(const short8*)(W + (size_t)(gate * HH + c0 + j) * HH + ko);
  }
  __syncthreads();

  const float* bi = (gru == 0) ? bih_h : bih_p;
  const float* bh = (gru == 0) ? bhh_h : bhh_p;
  const int col = c0 + (l & 15);
  const float bir = bi[col],        bhr = bh[col];
  const float biz = bi[HH + col],   bhz = bh[HH + col];
  const float bin = bi[2*HH + col], bhn = bh[2*HH + col];
  const int rowbase = w * 16 + (l >> 4) * 4;
  const int arow = w * 16 + (l & 15);
  const int lo8 = (l >> 4) * 8;

  // register-resident fp32 state for this thread's 4 (row,col) cells
  float hst[4];
  {
    const float* st0 = (gru == 0) ? g_h : g_pol;
#pragma unroll
    for (int reg = 0; reg < 4; ++reg) hst[reg] = st0[(rowbase + reg) * HH + col];
  }

  // gi prefetch for t=0
  const float* gibase = g_gi + (size_t)gru * G3 + col;
  float gir[4], giz[4], gin[4];
#pragma unroll
  for (int reg = 0; reg < 4; ++reg) {
    const float* gp = gibase + (size_t)(rowbase + reg) * NC;
    gir[reg] = gp[0]; giz[reg] = gp[HH]; gin[reg] = gp[2 * HH];
  }

  const int astr = (gru == 0) ? PK : HH;

  for (int t = 0; t < TT; ++t) {
    const __hip_bfloat16* __restrict__ Ab =
        (gru == 0) ? (g_pin_all + (size_t)t * NN * PK) : g_polm[t & 1];
    const __hip_bfloat16* __restrict__ arowp = Ab + (size_t)arow * astr + lo8;

    f32x4 acc0 = {}, acc1 = {}, acc2 = {};
    short8 aA[4], aB[4];
#define LOADA(dst, bk) { _Pragma("unroll") for (int q = 0; q < 4; ++q) \
      dst[q] = *(const short8*)(arowp + ((bk) + q) * 32); }
#define MFMA4(src, bk) { _Pragma("unroll") for (int q = 0; q < 4; ++q) { \
      const int k32 = (bk) + q; \
      short8 b0 = *(const short8*)(&Ws[( 0 + (l & 15)) * WLDS_STRIDE + k32 * 32 + lo8]); \
      short8 b1 = *(const short8*)(&Ws[(16 + (l & 15)) * WLDS_STRIDE + k32 * 32 + lo8]); \
      short8 b2 = *(const short8*)(&Ws[(32 + (l & 15)) * WLDS_STRIDE + k32 * 32 + lo8]); \
      acc0 = __builtin_amdgcn_mfma_f32_16x16x32_bf16(src[q], b0, acc0, 0, 0, 0); \
      acc1 = __builtin_amdgcn_mfma_f32_16x16x32_bf16(src[q], b1, acc1, 0, 0, 0); \
      acc2 = __builtin_amdgcn_mfma_f32_16x16x32_bf16(src[q], b2, acc2, 0, 0, 0); } }

    LOADA(aA, 0)
    LOADA(aB, 4)
    MFMA4(aA, 0)
    LOADA(aA, 8)
    MFMA4(aB, 4)
    LOADA(aB, 12)
    MFMA4(aA, 8)
    LOADA(aA, 16)
    MFMA4(aB, 12)
    LOADA(aB, 20)
    MFMA4(aA, 16)
    LOADA(aA, 24)
    MFMA4(aB, 20)
    LOADA(aB, 28)
    MFMA4(aA, 24)
    MFMA4(aB, 28)

    // prefetch gi for t+1 (recurrence-independent; hides under epilogue+barrier)
    float ngr[4], ngz[4], ngn[4];
    if (t < TT - 1) {
#pragma unroll
      for (int reg = 0; reg < 4; ++reg) {
        const float* gp = gibase + (size_t)((t + 1) * NN + rowbase + reg) * NC;
        ngr[reg] = gp[0]; ngz[reg] = gp[HH]; ngn[reg] = gp[2 * HH];
      }
    }

#pragma unroll
    for (int reg = 0; reg < 4; ++reg) {
      int row = rowbase + reg;
      float mk  = m_lds[t * NN + row];
      float mk1 = (t < TT - 1) ? m_lds[(t + 1) * NN + row] : 1.0f;
      float hm = hst[reg] * mk;
      float rg  = sigmoidf_(gir[reg] + acc0[reg] + bir + bhr);
      float z   = sigmoidf_(giz[reg] + acc1[reg] + biz + bhz);
      float nn2 = tanhf_  (gin[reg] + bin + rg * (acc2[reg] + bhn));
      float hv = (1.0f - z) * nn2 + z * hm;
      hst[reg] = hv;
      if (gru == 0) {
        g_pin_all[(size_t)(t + 1) * NN * PK + (size_t)row * PK + col] = __float2bfloat16(hv * mk1);
      } else {
        g_polm[(t + 1) & 1][row * HH + col] = __float2bfloat16(hv * mk1);
        out[POL_OFF + (size_t)(t * NN + row) * HH + col] = hv;
      }
    }
#pragma unroll
    for (int reg = 0; reg < 4; ++reg) { gir[reg] = ngr[reg]; giz[reg] = ngz[reg]; gin[reg] = ngn[reg]; }

    // ---- contention-free group barrier (skip after last step) ----
    if (t < TT - 1) {
      __syncthreads();   // all waves' stores issued (compiler drains vmcnt before s_barrier)
      if (tid == 0)
        __hip_atomic_store(&g_flags[gru][idx].v, (unsigned)(t + 1),
                           __ATOMIC_RELEASE, __HIP_MEMORY_SCOPE_AGENT);
      if (tid < 64) {
        while (__hip_atomic_load(&g_flags[gru][tid].v, __ATOMIC_RELAXED,
                                 __HIP_MEMORY_SCOPE_AGENT) < (unsigned)(t + 1))
          __builtin_amdgcn_s_sleep(2);
      }
      __threadfence();
      __syncthreads();
    }
  }

  // final fp32 state for final_kernel
  float* stf = (gru == 0) ? g_h : g_pol;
#pragma unroll
  for (int reg = 0; reg < 4; ++reg) stf[(rowbase + reg) * HH + col] = hst[reg];
}

// ---------------- post: ph_all = tanh(pin_all @ pw1.T + b1)   128x128 tile ----------------
__global__ __launch_bounds__(256) void pol_gemm(const float* __restrict__ pb1) {
  __shared__ __align__(16) __hip_bfloat16 As[2][128 * 72];
  __shared__ __align__(16) __hip_bfloat16 Bs[2][128 * 72];
  const int tid = threadIdx.x, l = tid & 63, w = tid >> 6;
  const int bm = blockIdx.x / 8, bn = blockIdx.x % 8;
  const __hip_bfloat16* A = g_pin_all + (size_t)bm * 128 * PK;
  const __hip_bfloat16* B = g_pw1_bf  + (size_t)bn * 128 * PK;
  const int roff = (w >> 1) * 64, coff = (w & 1) * 64;

  short8 ra[4], rb[4];
#define PL_LOAD(KT) { _Pragma("unroll") for (int q = 0; q < 4; ++q) { \
    int cch = q * 256 + tid; int row = cch >> 3, ko = (cch & 7) * 8; \
    ra[q] = *(const short8*)(A + (size_t)row * PK + (KT) * 64 + ko); \
    rb[q] = *(const short8*)(B + (size_t)row * PK + (KT) * 64 + ko); } }
#define PL_STORE(BUF) { _Pragma("unroll") for (int q = 0; q < 4; ++q) { \
    int cch = q * 256 + tid; int row = cch >> 3, ko = (cch & 7) * 8; \
    *(short8*)(&As[BUF][row * 72 + ko]) = ra[q]; \
    *(short8*)(&Bs[BUF][row * 72 + ko]) = rb[q]; } }

  PL_LOAD(0); PL_STORE(0);
  f32x4 acc[4][4] = {};
  for (int kt = 0; kt < 17; ++kt) {
    __syncthreads();
    if (kt < 16) PL_LOAD(kt + 1);
    const int buf = kt & 1;
#pragma unroll
    for (int ks = 0; ks < 2; ++ks) {
      short8 a[4], b[4];
#pragma unroll
      for (int fr = 0; fr < 4; ++fr)
        a[fr] = *(const short8*)(&As[buf][(roff + fr * 16 + (l & 15)) * 72 + ks * 32 + (l >> 4) * 8]);
#pragma unroll
      for (int fc = 0; fc < 4; ++fc)
        b[fc] = *(const short8*)(&Bs[buf][(coff + fc * 16 + (l & 15)) * 72 + ks * 32 + (l >> 4) * 8]);
#pragma unroll
      for (int fr = 0; fr < 4; ++fr)
#pragma unroll
        for (int fc = 0; fc < 4; ++fc)
          acc[fr][fc] = __builtin_amdgcn_mfma_f32_16x16x32_bf16(a[fr], b[fc], acc[fr][fc], 0, 0, 0);
    }
    if (kt < 16) PL_STORE((kt + 1) & 1);
  }
#pragma unroll
  for (int fc = 0; fc < 4; ++fc) {
    int col = bn * 128 + coff + fc * 16 + (l & 15);
    float b1v = pb1[col];
#pragma unroll
    for (int fr = 0; fr < 4; ++fr)
#pragma unroll
      for (int reg = 0; reg < 4; ++reg) {
        int row = bm * 128 + roff + fr * 16 + (l >> 4) * 4 + reg;
        g_ph_all[(size_t)row * HH + col] = __float2bfloat16(tanhf_(acc[fr][fc][reg] + b1v));
      }
  }
}

// ---------------- post: pdist = ph_all @ pw2.T + b2 ----------------
__global__ __launch_bounds__(256) void pdist_kernel(const float* __restrict__ pb2,
                                                    float* __restrict__ out) {
  const int tid = threadIdx.x, l = tid & 63, w = tid >> 6;
  const int r0 = blockIdx.x * 64;
  f32x4 pa = {};
  const __hip_bfloat16* PH = g_ph_all + (size_t)(r0 + w * 16 + (l & 15)) * HH;
  const __hip_bfloat16* B  = g_pw2_bf + (size_t)(l & 15) * HH;
#pragma unroll 4
  for (int k32 = 0; k32 < 32; ++k32) {
    short8 a = *(const short8*)(PH + k32 * 32 + (l >> 4) * 8);
    short8 b = *(const short8*)(B  + k32 * 32 + (l >> 4) * 8);
    pa = __builtin_amdgcn_mfma_f32_16x16x32_bf16(a, b, pa, 0, 0, 0);
  }
  int o = l & 15;
  float bb = pb2[o];
#pragma unroll
  for (int reg = 0; reg < 4; ++reg) {
    int row = r0 + w * 16 + (l >> 4) * 4 + reg;
    out[PD_OFF + (size_t)row * AA + o] = pa[reg] + bb;
  }
}

// ---------------- final: hxs output ----------------
__global__ __launch_bounds__(256) void final_kernel(float* __restrict__ out) {
  int f = blockIdx.x * 256 + threadIdx.x;   // < 131072
  int n = f >> 11, j = f & 2047;
  out[HXS_OFF + f] = (j < HH) ? g_h[n * HH + j] : g_pol[n * HH + (j - HH)];
}

extern "C" void kernel_launch(void* const* d_in, const int* in_sizes, int n_in,
                              void* d_out, int out_size, void* d_ws, size_t ws_size,
                              hipStream_t stream) {
  const float* c     = (const float*)d_in[0];
  const float* hxs   = (const float*)d_in[1];
  const float* masks = (const float*)d_in[2];
  const float* act   = (const float*)d_in[3];
  const float* wih_h = (const float*)d_in[4];
  const float* whh_h = (const float*)d_in[5];
  const float* bih_h = (const float*)d_in[6];
  const float* bhh_h = (const float*)d_in[7];
  const float* wih_p = (const float*)d_in[8];
  const float* whh_p = (const float*)d_in[9];
  const float* bih_p = (const float*)d_in[10];
  const float* bhh_p = (const float*)d_in[11];
  const float* pw1   = (const float*)d_in[12];
  const float* pb1   = (const float*)d_in[13];
  const float* pw2   = (const float*)d_in[14];
  const float* pb2   = (const float*)d_in[15];
  float* out = (float*)d_out;

  const int wlds_bytes = 48 * WLDS_STRIDE * 2;   // 99072
  hipFuncSetAttribute((const void*)step_persist,
                      hipFuncAttributeMaxDynamicSharedMemorySize, wlds_bytes);

  conv_all<<<4096, 256, 0, stream>>>(c, masks, act, wih_h, wih_p, whh_h, whh_p, pw1, pw2);
  init_kernel<<<256, 256, 0, stream>>>(hxs, masks);
  pre_gemm<<<3072, 256, 0, stream>>>();
  step_persist<<<NBLK, 256, wlds_bytes, stream>>>(masks, bih_h, bhh_h, bih_p, bhh_p, out);
  pol_gemm<<<512, 256, 0, stream>>>(pb1);
  pdist_kernel<<<128, 256, 0, stream>>>(pb2, out);
  final_kernel<<<512, 256, 0, stream>>>(out);
}

// Round 6
// 1664.905 us; speedup vs baseline: 2.8944x; 1.6261x over previous
//
#include <hip/hip_runtime.h>
#include <hip/hip_bf16.h>
#include <math.h>

#define TT 128
#define NN 64
#define HH 1024
#define AA 16
#define G3 3072          /* 3*HH */
#define NC 6144          /* combined gi cols */
#define PK 1088          /* padded policy K (1040 -> 1088 = 17*64), zero tail */
#define WLDS_STRIDE 1032 /* LDS stride for persistent weight tile */
#define NBLK 128         /* persistent grid */

#define PD_OFF  0
#define POL_OFF (TT*NN*AA)                  /* 131072 */
#define HXS_OFF (POL_OFF + TT*NN*HH)        /* 8519680 */

typedef __attribute__((ext_vector_type(8))) short short8;
typedef __attribute__((ext_vector_type(2))) unsigned long long ull2;
typedef __attribute__((ext_vector_type(4))) float f32x4;

// ---- persistent device buffers (fully rewritten every call) ----
__device__ __align__(16) __hip_bfloat16 g_c_bf[TT*NN*HH];
__device__ __align__(16) __hip_bfloat16 g_wihc_bf[NC*HH];
__device__ __align__(16) __hip_bfloat16 g_whh_bf[2][G3*HH];
__device__ __align__(16) __hip_bfloat16 g_pw1_bf[HH*PK];
__device__ __align__(16) __hip_bfloat16 g_pw2_bf[AA*HH];
__device__ float g_gi[(size_t)TT*NN*NC];                        // 201 MB fp32
__device__ float g_h[NN*HH];
__device__ float g_pol[NN*HH];
__device__ __align__(16) __hip_bfloat16 g_pin_all[(TT+1)*NN*PK]; // [h(t-1)*m_t | a_t*m_t | 0]
__device__ __align__(16) __hip_bfloat16 g_polm[2][NN*HH];
__device__ __align__(16) __hip_bfloat16 g_ph_all[TT*NN*HH];      // tanh(policy hidden), bf16

struct BarFlag { unsigned v; unsigned pad[31]; };                 // 128B per flag
__device__ BarFlag g_flags[2][64];

__device__ __forceinline__ float sigmoidf_(float x) { return 1.0f / (1.0f + __expf(-x)); }
__device__ __forceinline__ float tanhf_(float x) {
  float e = __expf(2.0f * x);
  return 1.0f - 2.0f / (e + 1.0f);
}

// ---------------- conversions ----------------
__global__ __launch_bounds__(256) void conv_all(
    const float* __restrict__ c, const float* __restrict__ masks, const float* __restrict__ act,
    const float* __restrict__ wih_h, const float* __restrict__ wih_p,
    const float* __restrict__ whh_h, const float* __restrict__ whh_p,
    const float* __restrict__ pw1, const float* __restrict__ pw2)
{
  size_t i = (size_t)blockIdx.x * 256 + threadIdx.x;
  size_t stride = (size_t)gridDim.x * 256;
  for (size_t f = i; f < (size_t)TT*NN*HH; f += stride) g_c_bf[f] = __float2bfloat16(c[f]);
  for (size_t f = i; f < (size_t)G3*HH; f += stride) {
    g_wihc_bf[f]                 = __float2bfloat16(wih_h[f]);
    g_wihc_bf[(size_t)G3*HH + f] = __float2bfloat16(wih_p[f]);
    g_whh_bf[0][f] = __float2bfloat16(whh_h[f]);
    g_whh_bf[1][f] = __float2bfloat16(whh_p[f]);
  }
  for (size_t f = i; f < (size_t)HH*PK; f += stride) {
    int o = (int)(f / PK), j = (int)(f % PK);
    g_pw1_bf[f] = (j < HH + AA) ? __float2bfloat16(pw1[(size_t)o*(HH+AA) + j]) : __float2bfloat16(0.0f);
  }
  for (size_t f = i; f < (size_t)AA*HH; f += stride) g_pw2_bf[f] = __float2bfloat16(pw2[f]);
  for (size_t f = i; f < (size_t)TT*NN*(PK-HH); f += stride) {
    int row = (int)(f >> 6), j = (int)(f & 63);
    float v = (j < AA) ? act[(size_t)row*AA + j] * masks[row] : 0.0f;
    g_pin_all[(size_t)row*PK + HH + j] = __float2bfloat16(v);
  }
}

__global__ __launch_bounds__(256) void init_kernel(const float* __restrict__ hxs,
                                                   const float* __restrict__ masks) {
  int f = blockIdx.x * 256 + threadIdx.x;      // NN*HH threads
  int n = f >> 10, j = f & 1023;
  float m0 = masks[n];
  float hv = hxs[n * 2 * HH + j];
  float pv = hxs[n * 2 * HH + HH + j];
  g_h[f] = hv;
  g_pol[f] = pv;
  g_pin_all[(size_t)n * PK + j] = __float2bfloat16(hv * m0);
  g_polm[0][n * HH + j]         = __float2bfloat16(pv * m0);
  if (f < 128)
    __hip_atomic_store(&g_flags[f >> 6][f & 63].v, 0u,
                       __ATOMIC_RELAXED, __HIP_MEMORY_SCOPE_AGENT);
}

// ---------------- pre_gemm: gi = c @ [wih_h;wih_p].T   128x128 tile, BK=64, dbuf ----------------
__global__ __launch_bounds__(256) void pre_gemm() {
  __shared__ __align__(16) __hip_bfloat16 As[2][128 * 72];
  __shared__ __align__(16) __hip_bfloat16 Bs[2][128 * 72];
  const int tid = threadIdx.x, l = tid & 63, w = tid >> 6;
  const int bm = blockIdx.x / 48, bn = blockIdx.x % 48;
  const __hip_bfloat16* A = g_c_bf    + (size_t)bm * 128 * HH;
  const __hip_bfloat16* B = g_wihc_bf + (size_t)bn * 128 * HH;
  const int roff = (w >> 1) * 64, coff = (w & 1) * 64;

  short8 ra[4], rb[4];
#define PG_LOAD(KT) { _Pragma("unroll") for (int q = 0; q < 4; ++q) { \
    int cch = q * 256 + tid; int row = cch >> 3, ko = (cch & 7) * 8; \
    ra[q] = *(const short8*)(A + (size_t)row * HH + (KT) * 64 + ko); \
    rb[q] = *(const short8*)(B + (size_t)row * HH + (KT) * 64 + ko); } }
#define PG_STORE(BUF) { _Pragma("unroll") for (int q = 0; q < 4; ++q) { \
    int cch = q * 256 + tid; int row = cch >> 3, ko = (cch & 7) * 8; \
    *(short8*)(&As[BUF][row * 72 + ko]) = ra[q]; \
    *(short8*)(&Bs[BUF][row * 72 + ko]) = rb[q]; } }

  PG_LOAD(0); PG_STORE(0);
  f32x4 acc[4][4] = {};
  for (int kt = 0; kt < 16; ++kt) {
    __syncthreads();
    if (kt < 15) PG_LOAD(kt + 1);
    const int buf = kt & 1;
#pragma unroll
    for (int ks = 0; ks < 2; ++ks) {
      short8 a[4], b[4];
#pragma unroll
      for (int fr = 0; fr < 4; ++fr)
        a[fr] = *(const short8*)(&As[buf][(roff + fr * 16 + (l & 15)) * 72 + ks * 32 + (l >> 4) * 8]);
#pragma unroll
      for (int fc = 0; fc < 4; ++fc)
        b[fc] = *(const short8*)(&Bs[buf][(coff + fc * 16 + (l & 15)) * 72 + ks * 32 + (l >> 4) * 8]);
#pragma unroll
      for (int fr = 0; fr < 4; ++fr)
#pragma unroll
        for (int fc = 0; fc < 4; ++fc)
          acc[fr][fc] = __builtin_amdgcn_mfma_f32_16x16x32_bf16(a[fr], b[fc], acc[fr][fc], 0, 0, 0);
    }
    if (kt < 15) PG_STORE((kt + 1) & 1);
  }
#pragma unroll
  for (int fr = 0; fr < 4; ++fr)
#pragma unroll
    for (int fc = 0; fc < 4; ++fc)
#pragma unroll
      for (int reg = 0; reg < 4; ++reg) {
        int row = bm * 128 + roff + fr * 16 + (l >> 4) * 4 + reg;
        int col = bn * 128 + coff + fc * 16 + (l & 15);
        g_gi[(size_t)row * NC + col] = acc[fr][fc][reg];
      }
}

// ---------------- persistent 2-GRU scan kernel ----------------
// 128 blocks: 0..63 GRU-h (cols idx*16), 64..127 GRU-pol. Independent barrier per GRU group.
// All cross-block data goes through L3 via relaxed agent-scope atomics (sc1) — no L2 flushes.
__global__ __launch_bounds__(256) void step_persist(
    const float* __restrict__ masks,
    const float* __restrict__ bih_h, const float* __restrict__ bhh_h,
    const float* __restrict__ bih_p, const float* __restrict__ bhh_p,
    float* __restrict__ out)
{
  extern __shared__ __align__(16) __hip_bfloat16 Ws[];   // [48][WLDS_STRIDE]
  __shared__ float m_lds[TT * NN];                       // 32 KB masks
  __shared__ __align__(8) __hip_bfloat16 sL[NN * 16];    // 2 KB repack tile
  const int tid = threadIdx.x, l = tid & 63, w = tid >> 6;
  const int gru = blockIdx.x >> 6;
  const int idx = blockIdx.x & 63;
  const int c0  = idx * 16;
  const __hip_bfloat16* __restrict__ W = g_whh_bf[gru];

  for (int i = tid; i < TT * NN; i += 256) m_lds[i] = masks[i];

  // one-time weight staging: LDS row = gate*16 + j  <=  weight row gate*HH + c0 + j
  for (int ch = tid; ch < 48 * 128; ch += 256) {
    int row = ch >> 7, ko = (ch & 127) * 8;
    int gate = row >> 4, j = row & 15;
    *(short8*)(&Ws[row * WLDS_STRIDE + ko]) =
        *(const short8*)(W + (size_t)(gate * HH + c0 + j) * HH + ko);
  }
  __syncthreads();

  const float* bi = (gru == 0) ? bih_h : bih_p;
  const float* bh = (gru == 0) ? bhh_h : bhh_p;
  const int col = c0 + (l & 15);
  const float bir = bi[col],        bhr = bh[col];
  const float biz = bi[HH + col],   bhz = bh[HH + col];
  const float bin = bi[2*HH + col], bhn = bh[2*HH + col];
  const int rowbase = w * 16 + (l >> 4) * 4;
  const int arow = w * 16 + (l & 15);
  const int lo8 = (l >> 4) * 8;

  // register-resident fp32 state for this thread's 4 (row,col) cells
  float hst[4];
  {
    const float* st0 = (gru == 0) ? g_h : g_pol;
#pragma unroll
    for (int reg = 0; reg < 4; ++reg) hst[reg] = st0[(rowbase + reg) * HH + col];
  }

  // gi prefetch for t=0
  const float* gibase = g_gi + (size_t)gru * G3 + col;
  float gir[4], giz[4], gin[4];
#pragma unroll
  for (int reg = 0; reg < 4; ++reg) {
    const float* gp = gibase + (size_t)(rowbase + reg) * NC;
    gir[reg] = gp[0]; giz[reg] = gp[HH]; gin[reg] = gp[2 * HH];
  }

  const int astr = (gru == 0) ? PK : HH;

  for (int t = 0; t < TT; ++t) {
    const __hip_bfloat16* __restrict__ Ab =
        (gru == 0) ? (g_pin_all + (size_t)t * NN * PK) : g_polm[t & 1];
    const __hip_bfloat16* __restrict__ arowp = Ab + (size_t)arow * astr + lo8;

    f32x4 acc0 = {}, acc1 = {}, acc2 = {};
    short8 aA[4], aB[4];
    // A loads: 8B relaxed agent-scope atomics (L2-bypassing, L3-coherent), fused to short8
#define LOADA(dst, bk) { _Pragma("unroll") for (int q = 0; q < 4; ++q) { \
      ull2 uu; \
      uu.x = __hip_atomic_load((const unsigned long long*)(arowp + ((bk) + q) * 32), \
                               __ATOMIC_RELAXED, __HIP_MEMORY_SCOPE_AGENT); \
      uu.y = __hip_atomic_load((const unsigned long long*)(arowp + ((bk) + q) * 32 + 4), \
                               __ATOMIC_RELAXED, __HIP_MEMORY_SCOPE_AGENT); \
      dst[q] = __builtin_bit_cast(short8, uu); } }
#define MFMA4(src, bk) { _Pragma("unroll") for (int q = 0; q < 4; ++q) { \
      const int k32 = (bk) + q; \
      short8 b0 = *(const short8*)(&Ws[( 0 + (l & 15)) * WLDS_STRIDE + k32 * 32 + lo8]); \
      short8 b1 = *(const short8*)(&Ws[(16 + (l & 15)) * WLDS_STRIDE + k32 * 32 + lo8]); \
      short8 b2 = *(const short8*)(&Ws[(32 + (l & 15)) * WLDS_STRIDE + k32 * 32 + lo8]); \
      acc0 = __builtin_amdgcn_mfma_f32_16x16x32_bf16(src[q], b0, acc0, 0, 0, 0); \
      acc1 = __builtin_amdgcn_mfma_f32_16x16x32_bf16(src[q], b1, acc1, 0, 0, 0); \
      acc2 = __builtin_amdgcn_mfma_f32_16x16x32_bf16(src[q], b2, acc2, 0, 0, 0); } }

    LOADA(aA, 0)
    LOADA(aB, 4)
    MFMA4(aA, 0)
    LOADA(aA, 8)
    MFMA4(aB, 4)
    LOADA(aB, 12)
    MFMA4(aA, 8)
    LOADA(aA, 16)
    MFMA4(aB, 12)
    LOADA(aB, 20)
    MFMA4(aA, 16)
    LOADA(aA, 24)
    MFMA4(aB, 20)
    LOADA(aB, 28)
    MFMA4(aA, 24)
    MFMA4(aB, 28)

    // prefetch gi for t+1 (recurrence-independent; normal cached loads)
    float ngr[4] = {}, ngz[4] = {}, ngn[4] = {};
    if (t < TT - 1) {
#pragma unroll
      for (int reg = 0; reg < 4; ++reg) {
        const float* gp = gibase + (size_t)((t + 1) * NN + rowbase + reg) * NC;
        ngr[reg] = gp[0]; ngz[reg] = gp[HH]; ngn[reg] = gp[2 * HH];
      }
    }

#pragma unroll
    for (int reg = 0; reg < 4; ++reg) {
      int row = rowbase + reg;
      float mk  = m_lds[t * NN + row];
      float mk1 = (t < TT - 1) ? m_lds[(t + 1) * NN + row] : 1.0f;
      float hm = hst[reg] * mk;
      float rg  = sigmoidf_(gir[reg] + acc0[reg] + bir + bhr);
      float z   = sigmoidf_(giz[reg] + acc1[reg] + biz + bhz);
      float nn2 = tanhf_  (gin[reg] + bin + rg * (acc2[reg] + bhn));
      float hv = (1.0f - z) * nn2 + z * hm;
      hst[reg] = hv;
      sL[row * 16 + (l & 15)] = __float2bfloat16(hv * mk1);   // repack tile
      if (gru == 1) out[POL_OFF + (size_t)(t * NN + row) * HH + col] = hv;  // normal cached store
    }
#pragma unroll
    for (int reg = 0; reg < 4; ++reg) { gir[reg] = ngr[reg]; giz[reg] = ngz[reg]; gin[reg] = ngn[reg]; }

    __syncthreads();   // sL complete
    // publish 64 rows x 16 cols as 8B agent-scope stores (to L3, no L2 flush needed)
    {
      int rr = tid >> 2, cc = tid & 3;
      unsigned long long v = *(const unsigned long long*)(&sL[rr * 16 + cc * 4]);
      __hip_bfloat16* dstp = (gru == 0)
          ? (g_pin_all + (size_t)(t + 1) * NN * PK + (size_t)rr * PK + c0 + cc * 4)
          : (g_polm[(t + 1) & 1] + (size_t)rr * HH + c0 + cc * 4);
      __hip_atomic_store((unsigned long long*)dstp, v,
                         __ATOMIC_RELAXED, __HIP_MEMORY_SCOPE_AGENT);
    }

    // ---- contention-free group barrier, no cache maintenance (skip after last step) ----
    if (t < TT - 1) {
      asm volatile("s_waitcnt vmcnt(0)" ::: "memory");   // this wave's stores are at L3
      __syncthreads();                                   // => all waves' stores are
      if (tid == 0)
        __hip_atomic_store(&g_flags[gru][idx].v, (unsigned)(t + 1),
                           __ATOMIC_RELAXED, __HIP_MEMORY_SCOPE_AGENT);
      if (tid < 64) {
        while (__hip_atomic_load(&g_flags[gru][tid].v, __ATOMIC_RELAXED,
                                 __HIP_MEMORY_SCOPE_AGENT) < (unsigned)(t + 1))
          __builtin_amdgcn_s_sleep(2);
      }
      __syncthreads();
    }
  }

  // final fp32 state for final_kernel
  float* stf = (gru == 0) ? g_h : g_pol;
#pragma unroll
  for (int reg = 0; reg < 4; ++reg) stf[(rowbase + reg) * HH + col] = hst[reg];
}

// ---------------- post: ph_all = tanh(pin_all @ pw1.T + b1)   128x128 tile ----------------
__global__ __launch_bounds__(256) void pol_gemm(const float* __restrict__ pb1) {
  __shared__ __align__(16) __hip_bfloat16 As[2][128 * 72];
  __shared__ __align__(16) __hip_bfloat16 Bs[2][128 * 72];
  const int tid = threadIdx.x, l = tid & 63, w = tid >> 6;
  const int bm = blockIdx.x / 8, bn = blockIdx.x % 8;
  const __hip_bfloat16* A = g_pin_all + (size_t)bm * 128 * PK;
  const __hip_bfloat16* B = g_pw1_bf  + (size_t)bn * 128 * PK;
  const int roff = (w >> 1) * 64, coff = (w & 1) * 64;

  short8 ra[4], rb[4];
#define PL_LOAD(KT) { _Pragma("unroll") for (int q = 0; q < 4; ++q) { \
    int cch = q * 256 + tid; int row = cch >> 3, ko = (cch & 7) * 8; \
    ra[q] = *(const short8*)(A + (size_t)row * PK + (KT) * 64 + ko); \
    rb[q] = *(const short8*)(B + (size_t)row * PK + (KT) * 64 + ko); } }
#define PL_STORE(BUF) { _Pragma("unroll") for (int q = 0; q < 4; ++q) { \
    int cch = q * 256 + tid; int row = cch >> 3, ko = (cch & 7) * 8; \
    *(short8*)(&As[BUF][row * 72 + ko]) = ra[q]; \
    *(short8*)(&Bs[BUF][row * 72 + ko]) = rb[q]; } }

  PL_LOAD(0); PL_STORE(0);
  f32x4 acc[4][4] = {};
  for (int kt = 0; kt < 17; ++kt) {
    __syncthreads();
    if (kt < 16) PL_LOAD(kt + 1);
    const int buf = kt & 1;
#pragma unroll
    for (int ks = 0; ks < 2; ++ks) {
      short8 a[4], b[4];
#pragma unroll
      for (int fr = 0; fr < 4; ++fr)
        a[fr] = *(const short8*)(&As[buf][(roff + fr * 16 + (l & 15)) * 72 + ks * 32 + (l >> 4) * 8]);
#pragma unroll
      for (int fc = 0; fc < 4; ++fc)
        b[fc] = *(const short8*)(&Bs[buf][(coff + fc * 16 + (l & 15)) * 72 + ks * 32 + (l >> 4) * 8]);
#pragma unroll
      for (int fr = 0; fr < 4; ++fr)
#pragma unroll
        for (int fc = 0; fc < 4; ++fc)
          acc[fr][fc] = __builtin_amdgcn_mfma_f32_16x16x32_bf16(a[fr], b[fc], acc[fr][fc], 0, 0, 0);
    }
    if (kt < 16) PL_STORE((kt + 1) & 1);
  }
#pragma unroll
  for (int fc = 0; fc < 4; ++fc) {
    int col = bn * 128 + coff + fc * 16 + (l & 15);
    float b1v = pb1[col];
#pragma unroll
    for (int fr = 0; fr < 4; ++fr)
#pragma unroll
      for (int reg = 0; reg < 4; ++reg) {
        int row = bm * 128 + roff + fr * 16 + (l >> 4) * 4 + reg;
        g_ph_all[(size_t)row * HH + col] = __float2bfloat16(tanhf_(acc[fr][fc][reg] + b1v));
      }
  }
}

// ---------------- post: pdist = ph_all @ pw2.T + b2 ----------------
__global__ __launch_bounds__(256) void pdist_kernel(const float* __restrict__ pb2,
                                                    float* __restrict__ out) {
  const int tid = threadIdx.x, l = tid & 63, w = tid >> 6;
  const int r0 = blockIdx.x * 64;
  f32x4 pa = {};
  const __hip_bfloat16* PH = g_ph_all + (size_t)(r0 + w * 16 + (l & 15)) * HH;
  const __hip_bfloat16* B  = g_pw2_bf + (size_t)(l & 15) * HH;
#pragma unroll 4
  for (int k32 = 0; k32 < 32; ++k32) {
    short8 a = *(const short8*)(PH + k32 * 32 + (l >> 4) * 8);
    short8 b = *(const short8*)(B  + k32 * 32 + (l >> 4) * 8);
    pa = __builtin_amdgcn_mfma_f32_16x16x32_bf16(a, b, pa, 0, 0, 0);
  }
  int o = l & 15;
  float bb = pb2[o];
#pragma unroll
  for (int reg = 0; reg < 4; ++reg) {
    int row = r0 + w * 16 + (l >> 4) * 4 + reg;
    out[PD_OFF + (size_t)row * AA + o] = pa[reg] + bb;
  }
}

// ---------------- final: hxs output ----------------
__global__ __launch_bounds__(256) void final_kernel(float* __restrict__ out) {
  int f = blockIdx.x * 256 + threadIdx.x;   // < 131072
  int n = f >> 11, j = f & 2047;
  out[HXS_OFF + f] = (j < HH) ? g_h[n * HH + j] : g_pol[n * HH + (j - HH)];
}

extern "C" void kernel_launch(void* const* d_in, const int* in_sizes, int n_in,
                              void* d_out, int out_size, void* d_ws, size_t ws_size,
                              hipStream_t stream) {
  const float* c     = (const float*)d_in[0];
  const float* hxs   = (const float*)d_in[1];
  const float* masks = (const float*)d_in[2];
  const float* act   = (const float*)d_in[3];
  const float* wih_h = (const float*)d_in[4];
  const float* whh_h = (const float*)d_in[5];
  const float* bih_h = (const float*)d_in[6];
  const float* bhh_h = (const float*)d_in[7];
  const float* wih_p = (const float*)d_in[8];
  const float* whh_p = (const float*)d_in[9];
  const float* bih_p = (const float*)d_in[10];
  const float* bhh_p = (const float*)d_in[11];
  const float* pw1   = (const float*)d_in[12];
  const float* pb1   = (const float*)d_in[13];
  const float* pw2   = (const float*)d_in[14];
  const float* pb2   = (const float*)d_in[15];
  float* out = (float*)d_out;

  const int wlds_bytes = 48 * WLDS_STRIDE * 2;   // 99072
  (void)hipFuncSetAttribute((const void*)step_persist,
                            hipFuncAttributeMaxDynamicSharedMemorySize, wlds_bytes);

  conv_all<<<4096, 256, 0, stream>>>(c, masks, act, wih_h, wih_p, whh_h, whh_p, pw1, pw2);
  init_kernel<<<256, 256, 0, stream>>>(hxs, masks);
  pre_gemm<<<3072, 256, 0, stream>>>();
  step_persist<<<NBLK, 256, wlds_bytes, stream>>>(masks, bih_h, bhh_h, bih_p, bhh_p, out);
  pol_gemm<<<512, 256, 0, stream>>>(pb1);
  pdist_kernel<<<128, 256, 0, stream>>>(pb2, out);
  final_kernel<<<513 - 1, 256, 0, stream>>>(out);
}

// Round 7
// 1626.698 us; speedup vs baseline: 2.9624x; 1.0235x over previous
//
#include <hip/hip_runtime.h>
#include <hip/hip_bf16.h>
#include <math.h>

#define TT 128
#define NN 64
#define HH 1024
#define AA 16
#define G3 3072          /* 3*HH */
#define NC 6144          /* combined gi cols */
#define PK 1088          /* padded policy K (1040 -> 1088 = 17*64), zero tail */
#define WLDS_STRIDE 1032 /* LDS stride for persistent weight tile */
#define NBLK 128         /* persistent grid */
#define GISL 3072        /* gi2 floats per (colblock, t): 64 rows * 48 */

#define PD_OFF  0
#define POL_OFF (TT*NN*AA)                  /* 131072 */
#define HXS_OFF (POL_OFF + TT*NN*HH)        /* 8519680 */

typedef __attribute__((ext_vector_type(8))) short short8;
typedef __attribute__((ext_vector_type(2))) unsigned long long ull2;
typedef __attribute__((ext_vector_type(4))) float f32x4;

// ---- persistent device buffers (fully rewritten every call) ----
__device__ __align__(16) __hip_bfloat16 g_c_bf[TT*NN*HH];
__device__ __align__(16) __hip_bfloat16 g_wihc_bf[NC*HH];
__device__ __align__(16) __hip_bfloat16 g_whh_bf[2][G3*HH];
__device__ __align__(16) __hip_bfloat16 g_pw1_bf[HH*PK];
__device__ __align__(16) __hip_bfloat16 g_pw2_bf[AA*HH];
__device__ float g_gi2[(size_t)2*64*TT*GISL];                   // 201 MB, consumer-contiguous
__device__ float g_h[NN*HH];
__device__ float g_pol[NN*HH];
__device__ __align__(16) __hip_bfloat16 g_pin_all[(TT+1)*NN*PK]; // [h(t-1)*m_t | a_t*m_t | 0]
__device__ __align__(16) __hip_bfloat16 g_polm[2][NN*HH];
__device__ __align__(16) __hip_bfloat16 g_ph_all[TT*NN*HH];      // tanh(policy hidden), bf16

struct BarFlag { unsigned v; unsigned pad[31]; };                 // 128B per flag
__device__ BarFlag g_flags[2][64];

__device__ __forceinline__ float sigmoidf_(float x) { return 1.0f / (1.0f + __expf(-x)); }
__device__ __forceinline__ float tanhf_(float x) {
  float e = __expf(2.0f * x);
  return 1.0f - 2.0f / (e + 1.0f);
}

// ---------------- conversions ----------------
__global__ __launch_bounds__(256) void conv_all(
    const float* __restrict__ c, const float* __restrict__ masks, const float* __restrict__ act,
    const float* __restrict__ wih_h, const float* __restrict__ wih_p,
    const float* __restrict__ whh_h, const float* __restrict__ whh_p,
    const float* __restrict__ pw1, const float* __restrict__ pw2)
{
  size_t i = (size_t)blockIdx.x * 256 + threadIdx.x;
  size_t stride = (size_t)gridDim.x * 256;
  for (size_t f = i; f < (size_t)TT*NN*HH; f += stride) g_c_bf[f] = __float2bfloat16(c[f]);
  for (size_t f = i; f < (size_t)G3*HH; f += stride) {
    g_wihc_bf[f]                 = __float2bfloat16(wih_h[f]);
    g_wihc_bf[(size_t)G3*HH + f] = __float2bfloat16(wih_p[f]);
    g_whh_bf[0][f] = __float2bfloat16(whh_h[f]);
    g_whh_bf[1][f] = __float2bfloat16(whh_p[f]);
  }
  for (size_t f = i; f < (size_t)HH*PK; f += stride) {
    int o = (int)(f / PK), j = (int)(f % PK);
    g_pw1_bf[f] = (j < HH + AA) ? __float2bfloat16(pw1[(size_t)o*(HH+AA) + j]) : __float2bfloat16(0.0f);
  }
  for (size_t f = i; f < (size_t)AA*HH; f += stride) g_pw2_bf[f] = __float2bfloat16(pw2[f]);
  for (size_t f = i; f < (size_t)TT*NN*(PK-HH); f += stride) {
    int row = (int)(f >> 6), j = (int)(f & 63);
    float v = (j < AA) ? act[(size_t)row*AA + j] * masks[row] : 0.0f;
    g_pin_all[(size_t)row*PK + HH + j] = __float2bfloat16(v);
  }
}

__global__ __launch_bounds__(256) void init_kernel(const float* __restrict__ hxs,
                                                   const float* __restrict__ masks) {
  int f = blockIdx.x * 256 + threadIdx.x;      // NN*HH threads
  int n = f >> 10, j = f & 1023;
  float m0 = masks[n];
  float hv = hxs[n * 2 * HH + j];
  float pv = hxs[n * 2 * HH + HH + j];
  g_h[f] = hv;
  g_pol[f] = pv;
  g_pin_all[(size_t)n * PK + j] = __float2bfloat16(hv * m0);
  g_polm[0][n * HH + j]         = __float2bfloat16(pv * m0);
  if (f < 128)
    __hip_atomic_store(&g_flags[f >> 6][f & 63].v, 0u,
                       __ATOMIC_RELAXED, __HIP_MEMORY_SCOPE_AGENT);
}

// ---------------- pre_gemm: gi = c @ [wih_h;wih_p].T   128x128 tile, BK=64, dbuf ----------------
// epilogue scatters into consumer-contiguous g_gi2[(gru*64+cb)][t][row][gate*16+j]
__global__ __launch_bounds__(256) void pre_gemm() {
  __shared__ __align__(16) __hip_bfloat16 As[2][128 * 72];
  __shared__ __align__(16) __hip_bfloat16 Bs[2][128 * 72];
  const int tid = threadIdx.x, l = tid & 63, w = tid >> 6;
  const int bm = blockIdx.x / 48, bn = blockIdx.x % 48;
  const __hip_bfloat16* A = g_c_bf    + (size_t)bm * 128 * HH;
  const __hip_bfloat16* B = g_wihc_bf + (size_t)bn * 128 * HH;
  const int roff = (w >> 1) * 64, coff = (w & 1) * 64;

  short8 ra[4], rb[4];
#define PG_LOAD(KT) { _Pragma("unroll") for (int q = 0; q < 4; ++q) { \
    int cch = q * 256 + tid; int row = cch >> 3, ko = (cch & 7) * 8; \
    ra[q] = *(const short8*)(A + (size_t)row * HH + (KT) * 64 + ko); \
    rb[q] = *(const short8*)(B + (size_t)row * HH + (KT) * 64 + ko); } }
#define PG_STORE(BUF) { _Pragma("unroll") for (int q = 0; q < 4; ++q) { \
    int cch = q * 256 + tid; int row = cch >> 3, ko = (cch & 7) * 8; \
    *(short8*)(&As[BUF][row * 72 + ko]) = ra[q]; \
    *(short8*)(&Bs[BUF][row * 72 + ko]) = rb[q]; } }

  PG_LOAD(0); PG_STORE(0);
  f32x4 acc[4][4] = {};
  for (int kt = 0; kt < 16; ++kt) {
    __syncthreads();
    if (kt < 15) PG_LOAD(kt + 1);
    const int buf = kt & 1;
#pragma unroll
    for (int ks = 0; ks < 2; ++ks) {
      short8 a[4], b[4];
#pragma unroll
      for (int fr = 0; fr < 4; ++fr)
        a[fr] = *(const short8*)(&As[buf][(roff + fr * 16 + (l & 15)) * 72 + ks * 32 + (l >> 4) * 8]);
#pragma unroll
      for (int fc = 0; fc < 4; ++fc)
        b[fc] = *(const short8*)(&Bs[buf][(coff + fc * 16 + (l & 15)) * 72 + ks * 32 + (l >> 4) * 8]);
#pragma unroll
      for (int fr = 0; fr < 4; ++fr)
#pragma unroll
        for (int fc = 0; fc < 4; ++fc)
          acc[fr][fc] = __builtin_amdgcn_mfma_f32_16x16x32_bf16(a[fr], b[fc], acc[fr][fc], 0, 0, 0);
    }
    if (kt < 15) PG_STORE((kt + 1) & 1);
  }
#pragma unroll
  for (int fr = 0; fr < 4; ++fr)
#pragma unroll
    for (int fc = 0; fc < 4; ++fc) {
      int col = bn * 128 + coff + fc * 16 + (l & 15);
      int q   = col >> 10;            // gru*3 + gate
      int gru = (q >= 3), gate = q - 3 * gru;
      int hcol = col & 1023, cb = hcol >> 4, j = hcol & 15;
#pragma unroll
      for (int reg = 0; reg < 4; ++reg) {
        int grow = bm * 128 + roff + fr * 16 + (l >> 4) * 4 + reg;
        int t = grow >> 6, n = grow & 63;
        g_gi2[((size_t)(gru * 64 + cb) * TT + t) * GISL + n * 48 + gate * 16 + j] = acc[fr][fc][reg];
      }
    }
}

// ---------------- persistent 2-GRU scan kernel ----------------
// 128 blocks: 0..63 GRU-h (cols idx*16), 64..127 GRU-pol. Independent barrier per GRU group.
// Cross-block data through L3 via relaxed agent-scope atomics (sc1) — no L2 flushes.
__global__ __launch_bounds__(256, 1) void step_persist(
    const float* __restrict__ masks,
    const float* __restrict__ bih_h, const float* __restrict__ bhh_h,
    const float* __restrict__ bih_p, const float* __restrict__ bhh_p,
    float* __restrict__ out)
{
  extern __shared__ __align__(16) __hip_bfloat16 Ws[];   // [48][WLDS_STRIDE]
  __shared__ float m_lds[TT * NN];                       // 32 KB masks
  __shared__ __align__(8) __hip_bfloat16 sL[NN * 16];    // 2 KB repack tile
  const int tid = threadIdx.x, l = tid & 63, w = tid >> 6;
  const int gru = blockIdx.x >> 6;
  const int idx = blockIdx.x & 63;
  const int c0  = idx * 16;
  const __hip_bfloat16* __restrict__ W = g_whh_bf[gru];

  for (int i = tid; i < TT * NN; i += 256) m_lds[i] = masks[i];

  for (int ch = tid; ch < 48 * 128; ch += 256) {
    int row = ch >> 7, ko = (ch & 127) * 8;
    int gate = row >> 4, j = row & 15;
    *(short8*)(&Ws[row * WLDS_STRIDE + ko]) =
        *(const short8*)(W + (size_t)(gate * HH + c0 + j) * HH + ko);
  }
  __syncthreads();

  const float* bi = (gru == 0) ? bih_h : bih_p;
  const float* bh = (gru == 0) ? bhh_h : bhh_p;
  const int col = c0 + (l & 15);
  const float bir = bi[col],        bhr = bh[col];
  const float biz = bi[HH + col],   bhz = bh[HH + col];
  const float bin = bi[2*HH + col], bhn = bh[2*HH + col];
  const int rowbase = w * 16 + (l >> 4) * 4;
  const int arow = w * 16 + (l & 15);
  const int lo8 = (l >> 4) * 8;
  const int jj = l & 15;

  float hst[4];
  {
    const float* st0 = (gru == 0) ? g_h : g_pol;
#pragma unroll
    for (int reg = 0; reg < 4; ++reg) hst[reg] = st0[(rowbase + reg) * HH + col];
  }

  // consumer-contiguous gi slab for this block
  const float* __restrict__ gib = g_gi2 + (size_t)(gru * 64 + idx) * TT * GISL;

  float gir[4], giz[4], gin[4];
#pragma unroll
  for (int reg = 0; reg < 4; ++reg) {
    const float* gp = gib + (size_t)(rowbase + reg) * 48;       // t = 0
    gir[reg] = gp[jj]; giz[reg] = gp[16 + jj]; gin[reg] = gp[32 + jj];
  }

  const int astr = (gru == 0) ? PK : HH;

  for (int t = 0; t < TT; ++t) {
    const __hip_bfloat16* __restrict__ Ab =
        (gru == 0) ? (g_pin_all + (size_t)t * NN * PK) : g_polm[t & 1];
    const __hip_bfloat16* __restrict__ arowp = Ab + (size_t)arow * astr + lo8;

    // ---- issue ALL 64 A-loads up front (one exposed L3 latency) ----
    short8 av[32];
#pragma unroll
    for (int k32 = 0; k32 < 32; ++k32) {
      ull2 uu;
      uu.x = __hip_atomic_load((const unsigned long long*)(arowp + k32 * 32),
                               __ATOMIC_RELAXED, __HIP_MEMORY_SCOPE_AGENT);
      uu.y = __hip_atomic_load((const unsigned long long*)(arowp + k32 * 32 + 4),
                               __ATOMIC_RELAXED, __HIP_MEMORY_SCOPE_AGENT);
      av[k32] = __builtin_bit_cast(short8, uu);
    }

    f32x4 acc0 = {}, acc1 = {}, acc2 = {};
#pragma unroll
    for (int k32 = 0; k32 < 32; ++k32) {
      short8 b0 = *(const short8*)(&Ws[( 0 + jj) * WLDS_STRIDE + k32 * 32 + lo8]);
      short8 b1 = *(const short8*)(&Ws[(16 + jj) * WLDS_STRIDE + k32 * 32 + lo8]);
      short8 b2 = *(const short8*)(&Ws[(32 + jj) * WLDS_STRIDE + k32 * 32 + lo8]);
      acc0 = __builtin_amdgcn_mfma_f32_16x16x32_bf16(av[k32], b0, acc0, 0, 0, 0);
      acc1 = __builtin_amdgcn_mfma_f32_16x16x32_bf16(av[k32], b1, acc1, 0, 0, 0);
      acc2 = __builtin_amdgcn_mfma_f32_16x16x32_bf16(av[k32], b2, acc2, 0, 0, 0);
    }

#pragma unroll
    for (int reg = 0; reg < 4; ++reg) {
      int row = rowbase + reg;
      float mk  = m_lds[t * NN + row];
      float mk1 = (t < TT - 1) ? m_lds[(t + 1) * NN + row] : 1.0f;
      float hm = hst[reg] * mk;
      float rg  = sigmoidf_(gir[reg] + acc0[reg] + bir + bhr);
      float z   = sigmoidf_(giz[reg] + acc1[reg] + biz + bhz);
      float nn2 = tanhf_  (gin[reg] + bin + rg * (acc2[reg] + bhn));
      float hv = (1.0f - z) * nn2 + z * hm;
      hst[reg] = hv;
      sL[row * 16 + jj] = __float2bfloat16(hv * mk1);
      if (gru == 1) out[POL_OFF + (size_t)(t * NN + row) * HH + col] = hv;
    }

    __syncthreads();   // sL complete
    {
      int rr = tid >> 2, cc = tid & 3;
      unsigned long long v = *(const unsigned long long*)(&sL[rr * 16 + cc * 4]);
      __hip_bfloat16* dstp = (gru == 0)
          ? (g_pin_all + (size_t)(t + 1) * NN * PK + (size_t)rr * PK + c0 + cc * 4)
          : (g_polm[(t + 1) & 1] + (size_t)rr * HH + c0 + cc * 4);
      __hip_atomic_store((unsigned long long*)dstp, v,
                         __ATOMIC_RELAXED, __HIP_MEMORY_SCOPE_AGENT);
    }

    // ---- barrier + overlapped gi prefetch (skip after last step) ----
    if (t < TT - 1) {
      asm volatile("s_waitcnt vmcnt(0)" ::: "memory");   // publish (+out) drained
      __syncthreads();
      if (tid == 0)
        __hip_atomic_store(&g_flags[gru][idx].v, (unsigned)(t + 1),
                           __ATOMIC_RELAXED, __HIP_MEMORY_SCOPE_AGENT);
      if (tid < 64) {       // wave 0 polls; waves 1-3 go prefetch gi meanwhile
        while (__hip_atomic_load(&g_flags[gru][tid].v, __ATOMIC_RELAXED,
                                 __HIP_MEMORY_SCOPE_AGENT) < (unsigned)(t + 1))
          __builtin_amdgcn_s_sleep(2);
      }
      // gi prefetch for t+1 (waves 1-3 overlap wave0's poll; wave0's hides under next MFMA)
      const float* gpt = gib + (size_t)(t + 1) * GISL;
#pragma unroll
      for (int reg = 0; reg < 4; ++reg) {
        const float* gp = gpt + (size_t)(rowbase + reg) * 48;
        gir[reg] = gp[jj]; giz[reg] = gp[16 + jj]; gin[reg] = gp[32 + jj];
      }
      __syncthreads();
    }
  }

  float* stf = (gru == 0) ? g_h : g_pol;
#pragma unroll
  for (int reg = 0; reg < 4; ++reg) stf[(rowbase + reg) * HH + col] = hst[reg];
}

// ---------------- post: ph_all = tanh(pin_all @ pw1.T + b1)   128x128 tile ----------------
__global__ __launch_bounds__(256) void pol_gemm(const float* __restrict__ pb1) {
  __shared__ __align__(16) __hip_bfloat16 As[2][128 * 72];
  __shared__ __align__(16) __hip_bfloat16 Bs[2][128 * 72];
  const int tid = threadIdx.x, l = tid & 63, w = tid >> 6;
  const int bm = blockIdx.x / 8, bn = blockIdx.x % 8;
  const __hip_bfloat16* A = g_pin_all + (size_t)bm * 128 * PK;
  const __hip_bfloat16* B = g_pw1_bf  + (size_t)bn * 128 * PK;
  const int roff = (w >> 1) * 64, coff = (w & 1) * 64;

  short8 ra[4], rb[4];
#define PL_LOAD(KT) { _Pragma("unroll") for (int q = 0; q < 4; ++q) { \
    int cch = q * 256 + tid; int row = cch >> 3, ko = (cch & 7) * 8; \
    ra[q] = *(const short8*)(A + (size_t)row * PK + (KT) * 64 + ko); \
    rb[q] = *(const short8*)(B + (size_t)row * PK + (KT) * 64 + ko); } }
#define PL_STORE(BUF) { _Pragma("unroll") for (int q = 0; q < 4; ++q) { \
    int cch = q * 256 + tid; int row = cch >> 3, ko = (cch & 7) * 8; \
    *(short8*)(&As[BUF][row * 72 + ko]) = ra[q]; \
    *(short8*)(&Bs[BUF][row * 72 + ko]) = rb[q]; } }

  PL_LOAD(0); PL_STORE(0);
  f32x4 acc[4][4] = {};
  for (int kt = 0; kt < 17; ++kt) {
    __syncthreads();
    if (kt < 16) PL_LOAD(kt + 1);
    const int buf = kt & 1;
#pragma unroll
    for (int ks = 0; ks < 2; ++ks) {
      short8 a[4], b[4];
#pragma unroll
      for (int fr = 0; fr < 4; ++fr)
        a[fr] = *(const short8*)(&As[buf][(roff + fr * 16 + (l & 15)) * 72 + ks * 32 + (l >> 4) * 8]);
#pragma unroll
      for (int fc = 0; fc < 4; ++fc)
        b[fc] = *(const short8*)(&Bs[buf][(coff + fc * 16 + (l & 15)) * 72 + ks * 32 + (l >> 4) * 8]);
#pragma unroll
      for (int fr = 0; fr < 4; ++fr)
#pragma unroll
        for (int fc = 0; fc < 4; ++fc)
          acc[fr][fc] = __builtin_amdgcn_mfma_f32_16x16x32_bf16(a[fr], b[fc], acc[fr][fc], 0, 0, 0);
    }
    if (kt < 16) PL_STORE((kt + 1) & 1);
  }
#pragma unroll
  for (int fc = 0; fc < 4; ++fc) {
    int col = bn * 128 + coff + fc * 16 + (l & 15);
    float b1v = pb1[col];
#pragma unroll
    for (int fr = 0; fr < 4; ++fr)
#pragma unroll
      for (int reg = 0; reg < 4; ++reg) {
        int row = bm * 128 + roff + fr * 16 + (l >> 4) * 4 + reg;
        g_ph_all[(size_t)row * HH + col] = __float2bfloat16(tanhf_(acc[fr][fc][reg] + b1v));
      }
  }
}

// ---------------- post: pdist = ph_all @ pw2.T + b2 ----------------
__global__ __launch_bounds__(256) void pdist_kernel(const float* __restrict__ pb2,
                                                    float* __restrict__ out) {
  const int tid = threadIdx.x, l = tid & 63, w = tid >> 6;
  const int r0 = blockIdx.x * 64;
  f32x4 pa = {};
  const __hip_bfloat16* PH = g_ph_all + (size_t)(r0 + w * 16 + (l & 15)) * HH;
  const __hip_bfloat16* B  = g_pw2_bf + (size_t)(l & 15) * HH;
#pragma unroll 4
  for (int k32 = 0; k32 < 32; ++k32) {
    short8 a = *(const short8*)(PH + k32 * 32 + (l >> 4) * 8);
    short8 b = *(const short8*)(B  + k32 * 32 + (l >> 4) * 8);
    pa = __builtin_amdgcn_mfma_f32_16x16x32_bf16(a, b, pa, 0, 0, 0);
  }
  int o = l & 15;
  float bb = pb2[o];
#pragma unroll
  for (int reg = 0; reg < 4; ++reg) {
    int row = r0 + w * 16 + (l >> 4) * 4 + reg;
    out[PD_OFF + (size_t)row * AA + o] = pa[reg] + bb;
  }
}

// ---------------- final: hxs output ----------------
__global__ __launch_bounds__(256) void final_kernel(float* __restrict__ out) {
  int f = blockIdx.x * 256 + threadIdx.x;   // < 131072
  int n = f >> 11, j = f & 2047;
  out[HXS_OFF + f] = (j < HH) ? g_h[n * HH + j] : g_pol[n * HH + (j - HH)];
}

extern "C" void kernel_launch(void* const* d_in, const int* in_sizes, int n_in,
                              void* d_out, int out_size, void* d_ws, size_t ws_size,
                              hipStream_t stream) {
  const float* c     = (const float*)d_in[0];
  const float* hxs   = (const float*)d_in[1];
  const float* masks = (const float*)d_in[2];
  const float* act   = (const float*)d_in[3];
  const float* wih_h = (const float*)d_in[4];
  const float* whh_h = (const float*)d_in[5];
  const float* bih_h = (const float*)d_in[6];
  const float* bhh_h = (const float*)d_in[7];
  const float* wih_p = (const float*)d_in[8];
  const float* whh_p = (const float*)d_in[9];
  const float* bih_p = (const float*)d_in[10];
  const float* bhh_p = (const float*)d_in[11];
  const float* pw1   = (const float*)d_in[12];
  const float* pb1   = (const float*)d_in[13];
  const float* pw2   = (const float*)d_in[14];
  const float* pb2   = (const float*)d_in[15];
  float* out = (float*)d_out;

  const int wlds_bytes = 48 * WLDS_STRIDE * 2;   // 99072
  (void)hipFuncSetAttribute((const void*)step_persist,
                            hipFuncAttributeMaxDynamicSharedMemorySize, wlds_bytes);

  conv_all<<<4096, 256, 0, stream>>>(c, masks, act, wih_h, wih_p, whh_h, whh_p, pw1, pw2);
  init_kernel<<<256, 256, 0, stream>>>(hxs, masks);
  pre_gemm<<<3072, 256, 0, stream>>>();
  step_persist<<<NBLK, 256, wlds_bytes, stream>>>(masks, bih_h, bhh_h, bih_p, bhh_p, out);
  pol_gemm<<<512, 256, 0, stream>>>(pb1);
  pdist_kernel<<<128, 256, 0, stream>>>(pb2, out);
  final_kernel<<<512, 256, 0, stream>>>(out);
}

// Round 8
// 1552.332 us; speedup vs baseline: 3.1043x; 1.0479x over previous
//
#include <hip/hip_runtime.h>
#include <hip/hip_bf16.h>
#include <math.h>

#define TT 128
#define NN 64
#define HH 1024
#define AA 16
#define G3 3072          /* 3*HH */
#define NC 6144          /* combined gi cols */
#define PK 1088          /* padded policy K (1040 -> 1088 = 17*64), zero tail */
#define WLDS_STRIDE 1032 /* LDS stride for persistent weight tile (2064B, 16B-aligned rows) */
#define NBLK 128         /* persistent grid */
#define GISL 3072        /* gi2 floats per (colblock, t): 64 rows * 48 */

#define PD_OFF  0
#define POL_OFF (TT*NN*AA)                  /* 131072 */
#define HXS_OFF (POL_OFF + TT*NN*HH)        /* 8519680 */

typedef __attribute__((ext_vector_type(8))) short short8;
typedef __attribute__((ext_vector_type(2))) unsigned long long ull2;
typedef __attribute__((ext_vector_type(4))) float f32x4;

// ---- persistent device buffers (fully rewritten every call) ----
__device__ __align__(16) __hip_bfloat16 g_c_bf[TT*NN*HH];
__device__ __align__(16) __hip_bfloat16 g_wihc_bf[NC*HH];
__device__ __align__(16) __hip_bfloat16 g_whh_bf[2][G3*HH];
__device__ __align__(16) __hip_bfloat16 g_pw1_bf[HH*PK];
__device__ __align__(16) __hip_bfloat16 g_pw2_bf[AA*HH];
__device__ float g_gi2[(size_t)2*64*TT*GISL];                   // 201 MB, consumer-contiguous
__device__ float g_h[NN*HH];
__device__ float g_pol[NN*HH];
__device__ __align__(16) __hip_bfloat16 g_pin_all[(TT+1)*NN*PK]; // [h(t-1)*m_t | a_t*m_t | 0]
__device__ __align__(16) __hip_bfloat16 g_polm[2][NN*HH];
__device__ __align__(16) __hip_bfloat16 g_ph_all[TT*NN*HH];      // tanh(policy hidden), bf16

struct BarFlag { unsigned v; unsigned pad[31]; };                 // 128B per flag
__device__ BarFlag g_flags[2][64];

__device__ __forceinline__ float sigmoidf_(float x) { return 1.0f / (1.0f + __expf(-x)); }
__device__ __forceinline__ float tanhf_(float x) {
  float e = __expf(2.0f * x);
  return 1.0f - 2.0f / (e + 1.0f);
}

// ---------------- conversions ----------------
__global__ __launch_bounds__(256) void conv_all(
    const float* __restrict__ c, const float* __restrict__ masks, const float* __restrict__ act,
    const float* __restrict__ wih_h, const float* __restrict__ wih_p,
    const float* __restrict__ whh_h, const float* __restrict__ whh_p,
    const float* __restrict__ pw1, const float* __restrict__ pw2)
{
  size_t i = (size_t)blockIdx.x * 256 + threadIdx.x;
  size_t stride = (size_t)gridDim.x * 256;
  for (size_t f = i; f < (size_t)TT*NN*HH; f += stride) g_c_bf[f] = __float2bfloat16(c[f]);
  for (size_t f = i; f < (size_t)G3*HH; f += stride) {
    g_wihc_bf[f]                 = __float2bfloat16(wih_h[f]);
    g_wihc_bf[(size_t)G3*HH + f] = __float2bfloat16(wih_p[f]);
    g_whh_bf[0][f] = __float2bfloat16(whh_h[f]);
    g_whh_bf[1][f] = __float2bfloat16(whh_p[f]);
  }
  for (size_t f = i; f < (size_t)HH*PK; f += stride) {
    int o = (int)(f / PK), j = (int)(f % PK);
    g_pw1_bf[f] = (j < HH + AA) ? __float2bfloat16(pw1[(size_t)o*(HH+AA) + j]) : __float2bfloat16(0.0f);
  }
  for (size_t f = i; f < (size_t)AA*HH; f += stride) g_pw2_bf[f] = __float2bfloat16(pw2[f]);
  for (size_t f = i; f < (size_t)TT*NN*(PK-HH); f += stride) {
    int row = (int)(f >> 6), j = (int)(f & 63);
    float v = (j < AA) ? act[(size_t)row*AA + j] * masks[row] : 0.0f;
    g_pin_all[(size_t)row*PK + HH + j] = __float2bfloat16(v);
  }
}

__global__ __launch_bounds__(256) void init_kernel(const float* __restrict__ hxs,
                                                   const float* __restrict__ masks) {
  int f = blockIdx.x * 256 + threadIdx.x;      // NN*HH threads
  int n = f >> 10, j = f & 1023;
  float m0 = masks[n];
  float hv = hxs[n * 2 * HH + j];
  float pv = hxs[n * 2 * HH + HH + j];
  g_h[f] = hv;
  g_pol[f] = pv;
  g_pin_all[(size_t)n * PK + j] = __float2bfloat16(hv * m0);
  g_polm[0][n * HH + j]         = __float2bfloat16(pv * m0);
  if (f < 128)
    __hip_atomic_store(&g_flags[f >> 6][f & 63].v, 0u,
                       __ATOMIC_RELAXED, __HIP_MEMORY_SCOPE_AGENT);
}

// ---------------- pre_gemm: gi = c @ [wih_h;wih_p].T   128x128 tile, BK=64, dbuf ----------------
// epilogue scatters into consumer-contiguous g_gi2[(gru*64+cb)][t][row][gate*16+j]
__global__ __launch_bounds__(256) void pre_gemm() {
  __shared__ __align__(16) __hip_bfloat16 As[2][128 * 72];
  __shared__ __align__(16) __hip_bfloat16 Bs[2][128 * 72];
  const int tid = threadIdx.x, l = tid & 63, w = tid >> 6;
  const int bm = blockIdx.x / 48, bn = blockIdx.x % 48;
  const __hip_bfloat16* A = g_c_bf    + (size_t)bm * 128 * HH;
  const __hip_bfloat16* B = g_wihc_bf + (size_t)bn * 128 * HH;
  const int roff = (w >> 1) * 64, coff = (w & 1) * 64;

  short8 ra[4], rb[4];
#define PG_LOAD(KT) { _Pragma("unroll") for (int q = 0; q < 4; ++q) { \
    int cch = q * 256 + tid; int row = cch >> 3, ko = (cch & 7) * 8; \
    ra[q] = *(const short8*)(A + (size_t)row * HH + (KT) * 64 + ko); \
    rb[q] = *(const short8*)(B + (size_t)row * HH + (KT) * 64 + ko); } }
#define PG_STORE(BUF) { _Pragma("unroll") for (int q = 0; q < 4; ++q) { \
    int cch = q * 256 + tid; int row = cch >> 3, ko = (cch & 7) * 8; \
    *(short8*)(&As[BUF][row * 72 + ko]) = ra[q]; \
    *(short8*)(&Bs[BUF][row * 72 + ko]) = rb[q]; } }

  PG_LOAD(0); PG_STORE(0);
  f32x4 acc[4][4] = {};
  for (int kt = 0; kt < 16; ++kt) {
    __syncthreads();
    if (kt < 15) PG_LOAD(kt + 1);
    const int buf = kt & 1;
#pragma unroll
    for (int ks = 0; ks < 2; ++ks) {
      short8 a[4], b[4];
#pragma unroll
      for (int fr = 0; fr < 4; ++fr)
        a[fr] = *(const short8*)(&As[buf][(roff + fr * 16 + (l & 15)) * 72 + ks * 32 + (l >> 4) * 8]);
#pragma unroll
      for (int fc = 0; fc < 4; ++fc)
        b[fc] = *(const short8*)(&Bs[buf][(coff + fc * 16 + (l & 15)) * 72 + ks * 32 + (l >> 4) * 8]);
#pragma unroll
      for (int fr = 0; fr < 4; ++fr)
#pragma unroll
        for (int fc = 0; fc < 4; ++fc)
          acc[fr][fc] = __builtin_amdgcn_mfma_f32_16x16x32_bf16(a[fr], b[fc], acc[fr][fc], 0, 0, 0);
    }
    if (kt < 15) PG_STORE((kt + 1) & 1);
  }
#pragma unroll
  for (int fr = 0; fr < 4; ++fr)
#pragma unroll
    for (int fc = 0; fc < 4; ++fc) {
      int col = bn * 128 + coff + fc * 16 + (l & 15);
      int q   = col >> 10;            // gru*3 + gate
      int gru = (q >= 3), gate = q - 3 * gru;
      int hcol = col & 1023, cb = hcol >> 4, j = hcol & 15;
#pragma unroll
      for (int reg = 0; reg < 4; ++reg) {
        int grow = bm * 128 + roff + fr * 16 + (l >> 4) * 4 + reg;
        int t = grow >> 6, n = grow & 63;
        g_gi2[((size_t)(gru * 64 + cb) * TT + t) * GISL + n * 48 + gate * 16 + j] = acc[fr][fc][reg];
      }
    }
}

// ---------------- persistent 2-GRU scan kernel ----------------
// 128 blocks: 0..63 GRU-h (cols idx*16), 64..127 GRU-pol. Independent flag barrier per GRU group.
// Gates r,z weights live in 256 VGPRs; gate n stays in LDS. A-loads 16-deep pipelined sc1.
__global__ __launch_bounds__(256, 1) void step_persist(
    const float* __restrict__ masks,
    const float* __restrict__ bih_h, const float* __restrict__ bhh_h,
    const float* __restrict__ bih_p, const float* __restrict__ bhh_p,
    float* __restrict__ out)
{
  extern __shared__ __align__(16) __hip_bfloat16 Ws[];   // [48][WLDS_STRIDE]
  __shared__ float m_lds[TT * NN];                       // 32 KB masks
  __shared__ __align__(8) __hip_bfloat16 sL[NN * 16];    // 2 KB repack tile
  const int tid = threadIdx.x, l = tid & 63, w = tid >> 6;
  const int gru = blockIdx.x >> 6;
  const int idx = blockIdx.x & 63;
  const int c0  = idx * 16;
  const __hip_bfloat16* __restrict__ W = g_whh_bf[gru];

  for (int i = tid; i < TT * NN; i += 256) m_lds[i] = masks[i];

  for (int ch = tid; ch < 48 * 128; ch += 256) {
    int row = ch >> 7, ko = (ch & 127) * 8;
    int gate = row >> 4, j = row & 15;
    *(short8*)(&Ws[row * WLDS_STRIDE + ko]) =
        *(const short8*)(W + (size_t)(gate * HH + c0 + j) * HH + ko);
  }
  __syncthreads();

  const float* bi = (gru == 0) ? bih_h : bih_p;
  const float* bh = (gru == 0) ? bhh_h : bhh_p;
  const int col = c0 + (l & 15);
  const float bir = bi[col],        bhr = bh[col];
  const float biz = bi[HH + col],   bhz = bh[HH + col];
  const float bin = bi[2*HH + col], bhn = bh[2*HH + col];
  const int rowbase = w * 16 + (l >> 4) * 4;
  const int arow = w * 16 + (l & 15);
  const int lo8 = (l >> 4) * 8;
  const int jj = l & 15;

  // ---- load gates r,z weight fragments into registers (constant across all steps) ----
  short8 breg[64];
#pragma unroll
  for (int k32 = 0; k32 < 32; ++k32) {
    breg[k32 * 2 + 0] = *(const short8*)(&Ws[( 0 + jj) * WLDS_STRIDE + k32 * 32 + lo8]);
    breg[k32 * 2 + 1] = *(const short8*)(&Ws[(16 + jj) * WLDS_STRIDE + k32 * 32 + lo8]);
  }

  float hst[4];
  {
    const float* st0 = (gru == 0) ? g_h : g_pol;
#pragma unroll
    for (int reg = 0; reg < 4; ++reg) hst[reg] = st0[(rowbase + reg) * HH + col];
  }

  const float* __restrict__ gib = g_gi2 + (size_t)(gru * 64 + idx) * TT * GISL;
  float gir[4], giz[4], gin[4];
#pragma unroll
  for (int reg = 0; reg < 4; ++reg) {
    const float* gp = gib + (size_t)(rowbase + reg) * 48;       // t = 0
    gir[reg] = gp[jj]; giz[reg] = gp[16 + jj]; gin[reg] = gp[32 + jj];
  }

  const int astr = (gru == 0) ? PK : HH;

  for (int t = 0; t < TT; ++t) {
    const __hip_bfloat16* __restrict__ Ab =
        (gru == 0) ? (g_pin_all + (size_t)t * NN * PK) : g_polm[t & 1];
    const __hip_bfloat16* __restrict__ arowp = Ab + (size_t)arow * astr + lo8;

    short8 av[32];
#define LOAD_AV(U) { ull2 uu; \
      uu.x = __hip_atomic_load((const unsigned long long*)(arowp + (U) * 32), \
                               __ATOMIC_RELAXED, __HIP_MEMORY_SCOPE_AGENT); \
      uu.y = __hip_atomic_load((const unsigned long long*)(arowp + (U) * 32 + 4), \
                               __ATOMIC_RELAXED, __HIP_MEMORY_SCOPE_AGENT); \
      av[U] = __builtin_bit_cast(short8, uu); }

#pragma unroll
    for (int u = 0; u < 16; ++u) LOAD_AV(u)

    f32x4 acc0 = {}, acc1 = {}, acc2 = {};
#pragma unroll
    for (int u = 0; u < 32; ++u) {
      if (u + 16 < 32) LOAD_AV(u + 16)
      short8 bn2 = *(const short8*)(&Ws[(32 + jj) * WLDS_STRIDE + u * 32 + lo8]);
      acc0 = __builtin_amdgcn_mfma_f32_16x16x32_bf16(av[u], breg[u * 2 + 0], acc0, 0, 0, 0);
      acc1 = __builtin_amdgcn_mfma_f32_16x16x32_bf16(av[u], breg[u * 2 + 1], acc1, 0, 0, 0);
      acc2 = __builtin_amdgcn_mfma_f32_16x16x32_bf16(av[u], bn2, acc2, 0, 0, 0);
    }

    float hv_out[4];
#pragma unroll
    for (int reg = 0; reg < 4; ++reg) {
      int row = rowbase + reg;
      float mk  = m_lds[t * NN + row];
      float mk1 = (t < TT - 1) ? m_lds[(t + 1) * NN + row] : 1.0f;
      float hm = hst[reg] * mk;
      float rg  = sigmoidf_(gir[reg] + acc0[reg] + bir + bhr);
      float z   = sigmoidf_(giz[reg] + acc1[reg] + biz + bhz);
      float nn2 = tanhf_  (gin[reg] + bin + rg * (acc2[reg] + bhn));
      float hv = (1.0f - z) * nn2 + z * hm;
      hst[reg] = hv;
      hv_out[reg] = hv;
      sL[row * 16 + jj] = __float2bfloat16(hv * mk1);
    }

    __syncthreads();   // sL complete
    {
      int rr = tid >> 2, cc = tid & 3;
      unsigned long long v = *(const unsigned long long*)(&sL[rr * 16 + cc * 4]);
      __hip_bfloat16* dstp = (gru == 0)
          ? (g_pin_all + (size_t)(t + 1) * NN * PK + (size_t)rr * PK + c0 + cc * 4)
          : (g_polm[(t + 1) & 1] + (size_t)rr * HH + c0 + cc * 4);
      __hip_atomic_store((unsigned long long*)dstp, v,
                         __ATOMIC_RELAXED, __HIP_MEMORY_SCOPE_AGENT);
    }

    if (t < TT - 1) {
      asm volatile("s_waitcnt vmcnt(0)" ::: "memory");   // publish drained to L3
      __syncthreads();                                   // all waves drained
      if (tid == 0)
        __hip_atomic_store(&g_flags[gru][idx].v, (unsigned)(t + 1),
                           __ATOMIC_RELAXED, __HIP_MEMORY_SCOPE_AGENT);
      // out stores + gi prefetch AFTER the flag (overlap wave0's poll; not in drain window)
      if (gru == 1) {
#pragma unroll
        for (int reg = 0; reg < 4; ++reg)
          out[POL_OFF + (size_t)(t * NN + rowbase + reg) * HH + col] = hv_out[reg];
      }
      {
        const float* gpt = gib + (size_t)(t + 1) * GISL;
#pragma unroll
        for (int reg = 0; reg < 4; ++reg) {
          const float* gp = gpt + (size_t)(rowbase + reg) * 48;
          gir[reg] = gp[jj]; giz[reg] = gp[16 + jj]; gin[reg] = gp[32 + jj];
        }
      }
      if (tid < 64) {       // wave 0 polls; waves 1-3 proceed to the join barrier
        while (__hip_atomic_load(&g_flags[gru][tid].v, __ATOMIC_RELAXED,
                                 __HIP_MEMORY_SCOPE_AGENT) < (unsigned)(t + 1))
          __builtin_amdgcn_s_sleep(2);
      }
      __syncthreads();
    } else {
      if (gru == 1) {
#pragma unroll
        for (int reg = 0; reg < 4; ++reg)
          out[POL_OFF + (size_t)(t * NN + rowbase + reg) * HH + col] = hv_out[reg];
      }
    }
  }

  float* stf = (gru == 0) ? g_h : g_pol;
#pragma unroll
  for (int reg = 0; reg < 4; ++reg) stf[(rowbase + reg) * HH + col] = hst[reg];
}

// ---------------- post: ph_all = tanh(pin_all @ pw1.T + b1)   128x128 tile ----------------
__global__ __launch_bounds__(256) void pol_gemm(const float* __restrict__ pb1) {
  __shared__ __align__(16) __hip_bfloat16 As[2][128 * 72];
  __shared__ __align__(16) __hip_bfloat16 Bs[2][128 * 72];
  const int tid = threadIdx.x, l = tid & 63, w = tid >> 6;
  const int bm = blockIdx.x / 8, bn = blockIdx.x % 8;
  const __hip_bfloat16* A = g_pin_all + (size_t)bm * 128 * PK;
  const __hip_bfloat16* B = g_pw1_bf  + (size_t)bn * 128 * PK;
  const int roff = (w >> 1) * 64, coff = (w & 1) * 64;

  short8 ra[4], rb[4];
#define PL_LOAD(KT) { _Pragma("unroll") for (int q = 0; q < 4; ++q) { \
    int cch = q * 256 + tid; int row = cch >> 3, ko = (cch & 7) * 8; \
    ra[q] = *(const short8*)(A + (size_t)row * PK + (KT) * 64 + ko); \
    rb[q] = *(const short8*)(B + (size_t)row * PK + (KT) * 64 + ko); } }
#define PL_STORE(BUF) { _Pragma("unroll") for (int q = 0; q < 4; ++q) { \
    int cch = q * 256 + tid; int row = cch >> 3, ko = (cch & 7) * 8; \
    *(short8*)(&As[BUF][row * 72 + ko]) = ra[q]; \
    *(short8*)(&Bs[BUF][row * 72 + ko]) = rb[q]; } }

  PL_LOAD(0); PL_STORE(0);
  f32x4 acc[4][4] = {};
  for (int kt = 0; kt < 17; ++kt) {
    __syncthreads();
    if (kt < 16) PL_LOAD(kt + 1);
    const int buf = kt & 1;
#pragma unroll
    for (int ks = 0; ks < 2; ++ks) {
      short8 a[4], b[4];
#pragma unroll
      for (int fr = 0; fr < 4; ++fr)
        a[fr] = *(const short8*)(&As[buf][(roff + fr * 16 + (l & 15)) * 72 + ks * 32 + (l >> 4) * 8]);
#pragma unroll
      for (int fc = 0; fc < 4; ++fc)
        b[fc] = *(const short8*)(&Bs[buf][(coff + fc * 16 + (l & 15)) * 72 + ks * 32 + (l >> 4) * 8]);
#pragma unroll
      for (int fr = 0; fr < 4; ++fr)
#pragma unroll
        for (int fc = 0; fc < 4; ++fc)
          acc[fr][fc] = __builtin_amdgcn_mfma_f32_16x16x32_bf16(a[fr], b[fc], acc[fr][fc], 0, 0, 0);
    }
    if (kt < 16) PL_STORE((kt + 1) & 1);
  }
#pragma unroll
  for (int fc = 0; fc < 4; ++fc) {
    int col = bn * 128 + coff + fc * 16 + (l & 15);
    float b1v = pb1[col];
#pragma unroll
    for (int fr = 0; fr < 4; ++fr)
#pragma unroll
      for (int reg = 0; reg < 4; ++reg) {
        int row = bm * 128 + roff + fr * 16 + (l >> 4) * 4 + reg;
        g_ph_all[(size_t)row * HH + col] = __float2bfloat16(tanhf_(acc[fr][fc][reg] + b1v));
      }
  }
}

// ---------------- post: pdist = ph_all @ pw2.T + b2 ----------------
__global__ __launch_bounds__(256) void pdist_kernel(const float* __restrict__ pb2,
                                                    float* __restrict__ out) {
  const int tid = threadIdx.x, l = tid & 63, w = tid >> 6;
  const int r0 = blockIdx.x * 64;
  f32x4 pa = {};
  const __hip_bfloat16* PH = g_ph_all + (size_t)(r0 + w * 16 + (l & 15)) * HH;
  const __hip_bfloat16* B  = g_pw2_bf + (size_t)(l & 15) * HH;
#pragma unroll 4
  for (int k32 = 0; k32 < 32; ++k32) {
    short8 a = *(const short8*)(PH + k32 * 32 + (l >> 4) * 8);
    short8 b = *(const short8*)(B  + k32 * 32 + (l >> 4) * 8);
    pa = __builtin_amdgcn_mfma_f32_16x16x32_bf16(a, b, pa, 0, 0, 0);
  }
  int o = l & 15;
  float bb = pb2[o];
#pragma unroll
  for (int reg = 0; reg < 4; ++reg) {
    int row = r0 + w * 16 + (l >> 4) * 4 + reg;
    out[PD_OFF + (size_t)row * AA + o] = pa[reg] + bb;
  }
}

// ---------------- final: hxs output ----------------
__global__ __launch_bounds__(256) void final_kernel(float* __restrict__ out) {
  int f = blockIdx.x * 256 + threadIdx.x;   // < 131072
  int n = f >> 11, j = f & 2047;
  out[HXS_OFF + f] = (j < HH) ? g_h[n * HH + j] : g_pol[n * HH + (j - HH)];
}

extern "C" void kernel_launch(void* const* d_in, const int* in_sizes, int n_in,
                              void* d_out, int out_size, void* d_ws, size_t ws_size,
                              hipStream_t stream) {
  const float* c     = (const float*)d_in[0];
  const float* hxs   = (const float*)d_in[1];
  const float* masks = (const float*)d_in[2];
  const float* act   = (const float*)d_in[3];
  const float* wih_h = (const float*)d_in[4];
  const float* whh_h = (const float*)d_in[5];
  const float* bih_h = (const float*)d_in[6];
  const float* bhh_h = (const float*)d_in[7];
  const float* wih_p = (const float*)d_in[8];
  const float* whh_p = (const float*)d_in[9];
  const float* bih_p = (const float*)d_in[10];
  const float* bhh_p = (const float*)d_in[11];
  const float* pw1   = (const float*)d_in[12];
  const float* pb1   = (const float*)d_in[13];
  const float* pw2   = (const float*)d_in[14];
  const float* pb2   = (const float*)d_in[15];
  float* out = (float*)d_out;

  const int wlds_bytes = 48 * WLDS_STRIDE * 2;   // 99072
  (void)hipFuncSetAttribute((const void*)step_persist,
                            hipFuncAttributeMaxDynamicSharedMemorySize, wlds_bytes);

  conv_all<<<4096, 256, 0, stream>>>(c, masks, act, wih_h, wih_p, whh_h, whh_p, pw1, pw2);
  init_kernel<<<256, 256, 0, stream>>>(hxs, masks);
  pre_gemm<<<3072, 256, 0, stream>>>();
  step_persist<<<NBLK, 256, wlds_bytes, stream>>>(masks, bih_h, bhh_h, bih_p, bhh_p, out);
  pol_gemm<<<512, 256, 0, stream>>>(pb1);
  pdist_kernel<<<128, 256, 0, stream>>>(pb2, out);
  final_kernel<<<512, 256, 0, stream>>>(out);
}

// Round 9
// 1529.313 us; speedup vs baseline: 3.1510x; 1.0151x over previous
//
#include <hip/hip_runtime.h>
#include <hip/hip_bf16.h>
#include <math.h>

#define TT 128
#define NN 64
#define HH 1024
#define AA 16
#define G3 3072          /* 3*HH */
#define NC 6144          /* combined gi cols */
#define PK 1088          /* padded policy K (1040 -> 1088 = 17*64), zero tail */
#define WLDS_STRIDE 1032 /* LDS stride for persistent weight tile */
#define NBLK 128         /* persistent grid */
#define GISL 3072        /* gi2 floats per (colblock, t): 64 rows * 48 */

#define PD_OFF  0
#define POL_OFF (TT*NN*AA)                  /* 131072 */
#define HXS_OFF (POL_OFF + TT*NN*HH)        /* 8519680 */

typedef __attribute__((ext_vector_type(8))) short short8;
typedef __attribute__((ext_vector_type(4))) float f32x4;

// ---- persistent device buffers (fully rewritten every call) ----
__device__ __align__(16) __hip_bfloat16 g_c_bf[TT*NN*HH];
__device__ __align__(16) __hip_bfloat16 g_wihc_bf[NC*HH];
__device__ __align__(16) __hip_bfloat16 g_whh_bf[2][G3*HH];
__device__ __align__(16) __hip_bfloat16 g_pw1_bf[HH*PK];
__device__ __align__(16) __hip_bfloat16 g_pw2_bf[AA*HH];
__device__ float g_gi2[(size_t)2*64*TT*GISL];                   // 201 MB, consumer-contiguous
__device__ float g_h[NN*HH];
__device__ float g_pol[NN*HH];
__device__ __align__(16) __hip_bfloat16 g_pin_all[(size_t)(TT+1)*NN*PK];  // [h(t-1)*m_t | a_t*m_t | 0]
__device__ __align__(16) __hip_bfloat16 g_polm_all[(size_t)(TT+1)*NN*HH]; // pol(t-1)*m_t, time-indexed
__device__ __align__(16) __hip_bfloat16 g_ph_all[TT*NN*HH];      // tanh(policy hidden), bf16

struct BarFlag { unsigned v; unsigned pad[31]; };                 // 128B per flag
__device__ BarFlag g_flags[2][64];

__device__ __forceinline__ float sigmoidf_(float x) { return 1.0f / (1.0f + __expf(-x)); }
__device__ __forceinline__ float tanhf_(float x) {
  float e = __expf(2.0f * x);
  return 1.0f - 2.0f / (e + 1.0f);
}

// ---------------- conversions ----------------
__global__ __launch_bounds__(256) void conv_all(
    const float* __restrict__ c, const float* __restrict__ masks, const float* __restrict__ act,
    const float* __restrict__ wih_h, const float* __restrict__ wih_p,
    const float* __restrict__ whh_h, const float* __restrict__ whh_p,
    const float* __restrict__ pw1, const float* __restrict__ pw2)
{
  size_t i = (size_t)blockIdx.x * 256 + threadIdx.x;
  size_t stride = (size_t)gridDim.x * 256;
  for (size_t f = i; f < (size_t)TT*NN*HH; f += stride) g_c_bf[f] = __float2bfloat16(c[f]);
  for (size_t f = i; f < (size_t)G3*HH; f += stride) {
    g_wihc_bf[f]                 = __float2bfloat16(wih_h[f]);
    g_wihc_bf[(size_t)G3*HH + f] = __float2bfloat16(wih_p[f]);
    g_whh_bf[0][f] = __float2bfloat16(whh_h[f]);
    g_whh_bf[1][f] = __float2bfloat16(whh_p[f]);
  }
  for (size_t f = i; f < (size_t)HH*PK; f += stride) {
    int o = (int)(f / PK), j = (int)(f % PK);
    g_pw1_bf[f] = (j < HH + AA) ? __float2bfloat16(pw1[(size_t)o*(HH+AA) + j]) : __float2bfloat16(0.0f);
  }
  for (size_t f = i; f < (size_t)AA*HH; f += stride) g_pw2_bf[f] = __float2bfloat16(pw2[f]);
  for (size_t f = i; f < (size_t)TT*NN*(PK-HH); f += stride) {
    int row = (int)(f >> 6), j = (int)(f & 63);
    float v = (j < AA) ? act[(size_t)row*AA + j] * masks[row] : 0.0f;
    g_pin_all[(size_t)row*PK + HH + j] = __float2bfloat16(v);
  }
}

__global__ __launch_bounds__(256) void init_kernel(const float* __restrict__ hxs,
                                                   const float* __restrict__ masks) {
  int f = blockIdx.x * 256 + threadIdx.x;      // NN*HH threads
  int n = f >> 10, j = f & 1023;
  float m0 = masks[n];
  float hv = hxs[n * 2 * HH + j];
  float pv = hxs[n * 2 * HH + HH + j];
  g_h[f] = hv;
  g_pol[f] = pv;
  g_pin_all[(size_t)n * PK + j] = __float2bfloat16(hv * m0);
  g_polm_all[(size_t)n * HH + j] = __float2bfloat16(pv * m0);
  if (f < 128)
    __hip_atomic_store(&g_flags[f >> 6][f & 63].v, 0u,
                       __ATOMIC_RELAXED, __HIP_MEMORY_SCOPE_AGENT);
}

// ---------------- pre_gemm: gi = c @ [wih_h;wih_p].T   128x128 tile, BK=64, dbuf ----------------
__global__ __launch_bounds__(256) void pre_gemm() {
  __shared__ __align__(16) __hip_bfloat16 As[2][128 * 72];
  __shared__ __align__(16) __hip_bfloat16 Bs[2][128 * 72];
  const int tid = threadIdx.x, l = tid & 63, w = tid >> 6;
  const int bm = blockIdx.x / 48, bn = blockIdx.x % 48;
  const __hip_bfloat16* A = g_c_bf    + (size_t)bm * 128 * HH;
  const __hip_bfloat16* B = g_wihc_bf + (size_t)bn * 128 * HH;
  const int roff = (w >> 1) * 64, coff = (w & 1) * 64;

  short8 ra[4], rb[4];
#define PG_LOAD(KT) { _Pragma("unroll") for (int q = 0; q < 4; ++q) { \
    int cch = q * 256 + tid; int row = cch >> 3, ko = (cch & 7) * 8; \
    ra[q] = *(const short8*)(A + (size_t)row * HH + (KT) * 64 + ko); \
    rb[q] = *(const short8*)(B + (size_t)row * HH + (KT) * 64 + ko); } }
#define PG_STORE(BUF) { _Pragma("unroll") for (int q = 0; q < 4; ++q) { \
    int cch = q * 256 + tid; int row = cch >> 3, ko = (cch & 7) * 8; \
    *(short8*)(&As[BUF][row * 72 + ko]) = ra[q]; \
    *(short8*)(&Bs[BUF][row * 72 + ko]) = rb[q]; } }

  PG_LOAD(0); PG_STORE(0);
  f32x4 acc[4][4] = {};
  for (int kt = 0; kt < 16; ++kt) {
    __syncthreads();
    if (kt < 15) PG_LOAD(kt + 1);
    const int buf = kt & 1;
#pragma unroll
    for (int ks = 0; ks < 2; ++ks) {
      short8 a[4], b[4];
#pragma unroll
      for (int fr = 0; fr < 4; ++fr)
        a[fr] = *(const short8*)(&As[buf][(roff + fr * 16 + (l & 15)) * 72 + ks * 32 + (l >> 4) * 8]);
#pragma unroll
      for (int fc = 0; fc < 4; ++fc)
        b[fc] = *(const short8*)(&Bs[buf][(coff + fc * 16 + (l & 15)) * 72 + ks * 32 + (l >> 4) * 8]);
#pragma unroll
      for (int fr = 0; fr < 4; ++fr)
#pragma unroll
        for (int fc = 0; fc < 4; ++fc)
          acc[fr][fc] = __builtin_amdgcn_mfma_f32_16x16x32_bf16(a[fr], b[fc], acc[fr][fc], 0, 0, 0);
    }
    if (kt < 15) PG_STORE((kt + 1) & 1);
  }
#pragma unroll
  for (int fr = 0; fr < 4; ++fr)
#pragma unroll
    for (int fc = 0; fc < 4; ++fc) {
      int col = bn * 128 + coff + fc * 16 + (l & 15);
      int q   = col >> 10;            // gru*3 + gate
      int gru = (q >= 3), gate = q - 3 * gru;
      int hcol = col & 1023, cb = hcol >> 4, j = hcol & 15;
#pragma unroll
      for (int reg = 0; reg < 4; ++reg) {
        int grow = bm * 128 + roff + fr * 16 + (l >> 4) * 4 + reg;
        int t = grow >> 6, n = grow & 63;
        g_gi2[((size_t)(gru * 64 + cb) * TT + t) * GISL + n * 48 + gate * 16 + j] = acc[fr][fc][reg];
      }
    }
}

// ---------------- persistent 2-GRU scan kernel ----------------
// 128 blocks: 0..63 GRU-h (cols idx*16), 64..127 GRU-pol. Independent flag barrier per GRU group.
// Producers publish via relaxed sc1 stores (L3 write-through). Consumers use PLAIN wide loads:
// A-slabs are time-indexed (first-touch per step) so consumer L2 can never hold stale data.
__global__ __launch_bounds__(256, 1) void step_persist(
    const float* __restrict__ masks,
    const float* __restrict__ bih_h, const float* __restrict__ bhh_h,
    const float* __restrict__ bih_p, const float* __restrict__ bhh_p,
    float* __restrict__ out)
{
  extern __shared__ __align__(16) __hip_bfloat16 Ws[];   // [48][WLDS_STRIDE]
  __shared__ float m_lds[TT * NN];                       // 32 KB masks
  __shared__ __align__(8) __hip_bfloat16 sL[NN * 16];    // 2 KB repack tile
  const int tid = threadIdx.x, l = tid & 63, w = tid >> 6;
  const int gru = blockIdx.x >> 6;
  const int idx = blockIdx.x & 63;
  const int c0  = idx * 16;
  const __hip_bfloat16* __restrict__ W = g_whh_bf[gru];

  for (int i = tid; i < TT * NN; i += 256) m_lds[i] = masks[i];

  for (int ch = tid; ch < 48 * 128; ch += 256) {
    int row = ch >> 7, ko = (ch & 127) * 8;
    int gate = row >> 4, j = row & 15;
    *(short8*)(&Ws[row * WLDS_STRIDE + ko]) =
        *(const short8*)(W + (size_t)(gate * HH + c0 + j) * HH + ko);
  }
  __syncthreads();

  const float* bi = (gru == 0) ? bih_h : bih_p;
  const float* bh = (gru == 0) ? bhh_h : bhh_p;
  const int col = c0 + (l & 15);
  const float bir = bi[col],        bhr = bh[col];
  const float biz = bi[HH + col],   bhz = bh[HH + col];
  const float bin = bi[2*HH + col], bhn = bh[2*HH + col];
  const int rowbase = w * 16 + (l >> 4) * 4;
  const int arow = w * 16 + (l & 15);
  const int lo8 = (l >> 4) * 8;
  const int jj = l & 15;

  // gates r,z weight fragments in registers (constant across all steps)
  short8 breg[64];
#pragma unroll
  for (int k32 = 0; k32 < 32; ++k32) {
    breg[k32 * 2 + 0] = *(const short8*)(&Ws[( 0 + jj) * WLDS_STRIDE + k32 * 32 + lo8]);
    breg[k32 * 2 + 1] = *(const short8*)(&Ws[(16 + jj) * WLDS_STRIDE + k32 * 32 + lo8]);
  }

  float hst[4];
  {
    const float* st0 = (gru == 0) ? g_h : g_pol;
#pragma unroll
    for (int reg = 0; reg < 4; ++reg) hst[reg] = st0[(rowbase + reg) * HH + col];
  }

  const float* __restrict__ gib = g_gi2 + (size_t)(gru * 64 + idx) * TT * GISL;
  float gir[4], giz[4], gin[4];
#pragma unroll
  for (int reg = 0; reg < 4; ++reg) {
    const float* gp = gib + (size_t)(rowbase + reg) * 48;       // t = 0
    gir[reg] = gp[jj]; giz[reg] = gp[16 + jj]; gin[reg] = gp[32 + jj];
  }

  const int astr = (gru == 0) ? PK : HH;

  for (int t = 0; t < TT; ++t) {
    const __hip_bfloat16* __restrict__ Ab =
        (gru == 0) ? (g_pin_all + (size_t)t * NN * PK)
                   : (g_polm_all + (size_t)t * NN * HH);
    const __hip_bfloat16* __restrict__ arowp = Ab + (size_t)arow * astr + lo8;

    // plain wide A-loads — compiler emits pipelined global_load_dwordx4
    short8 av[32];
#pragma unroll
    for (int u = 0; u < 32; ++u) av[u] = *(const short8*)(arowp + u * 32);

    f32x4 acc0 = {}, acc1 = {}, acc2 = {};
#pragma unroll
    for (int u = 0; u < 32; ++u) {
      short8 bn2 = *(const short8*)(&Ws[(32 + jj) * WLDS_STRIDE + u * 32 + lo8]);
      acc0 = __builtin_amdgcn_mfma_f32_16x16x32_bf16(av[u], breg[u * 2 + 0], acc0, 0, 0, 0);
      acc1 = __builtin_amdgcn_mfma_f32_16x16x32_bf16(av[u], breg[u * 2 + 1], acc1, 0, 0, 0);
      acc2 = __builtin_amdgcn_mfma_f32_16x16x32_bf16(av[u], bn2, acc2, 0, 0, 0);
    }

    float hv_out[4];
#pragma unroll
    for (int reg = 0; reg < 4; ++reg) {
      int row = rowbase + reg;
      float mk  = m_lds[t * NN + row];
      float mk1 = (t < TT - 1) ? m_lds[(t + 1) * NN + row] : 1.0f;
      float hm = hst[reg] * mk;
      float rg  = sigmoidf_(gir[reg] + acc0[reg] + bir + bhr);
      float z   = sigmoidf_(giz[reg] + acc1[reg] + biz + bhz);
      float nn2 = tanhf_  (gin[reg] + bin + rg * (acc2[reg] + bhn));
      float hv = (1.0f - z) * nn2 + z * hm;
      hst[reg] = hv;
      hv_out[reg] = hv;
      sL[row * 16 + jj] = __float2bfloat16(hv * mk1);
    }

    __syncthreads();   // sL complete
    {
      int rr = tid >> 2, cc = tid & 3;
      unsigned long long v = *(const unsigned long long*)(&sL[rr * 16 + cc * 4]);
      __hip_bfloat16* dstp = (gru == 0)
          ? (g_pin_all + (size_t)(t + 1) * NN * PK + (size_t)rr * PK + c0 + cc * 4)
          : (g_polm_all + (size_t)(t + 1) * NN * HH + (size_t)rr * HH + c0 + cc * 4);
      __hip_atomic_store((unsigned long long*)dstp, v,
                         __ATOMIC_RELAXED, __HIP_MEMORY_SCOPE_AGENT);
    }

    if (t < TT - 1) {
      asm volatile("s_waitcnt vmcnt(0)" ::: "memory");   // publish drained to L3
      __syncthreads();                                   // all waves drained
      if (tid == 0)
        __hip_atomic_store(&g_flags[gru][idx].v, (unsigned)(t + 1),
                           __ATOMIC_RELAXED, __HIP_MEMORY_SCOPE_AGENT);
      // out stores + gi prefetch after flag (overlap the poll)
      if (gru == 1) {
#pragma unroll
        for (int reg = 0; reg < 4; ++reg)
          out[POL_OFF + (size_t)(t * NN + rowbase + reg) * HH + col] = hv_out[reg];
      }
      {
        const float* gpt = gib + (size_t)(t + 1) * GISL;
#pragma unroll
        for (int reg = 0; reg < 4; ++reg) {
          const float* gp = gpt + (size_t)(rowbase + reg) * 48;
          gir[reg] = gp[jj]; giz[reg] = gp[16 + jj]; gin[reg] = gp[32 + jj];
        }
      }
      // all 4 waves poll (lane l watches flag l) — no wave waits on another's poll
      while (__hip_atomic_load(&g_flags[gru][l].v, __ATOMIC_RELAXED,
                               __HIP_MEMORY_SCOPE_AGENT) < (unsigned)(t + 1))
        __builtin_amdgcn_s_sleep(2);
      __syncthreads();
    } else {
      if (gru == 1) {
#pragma unroll
        for (int reg = 0; reg < 4; ++reg)
          out[POL_OFF + (size_t)(t * NN + rowbase + reg) * HH + col] = hv_out[reg];
      }
    }
  }

  float* stf = (gru == 0) ? g_h : g_pol;
#pragma unroll
  for (int reg = 0; reg < 4; ++reg) stf[(rowbase + reg) * HH + col] = hst[reg];
}

// ---------------- post: ph_all = tanh(pin_all @ pw1.T + b1)   128x128 tile ----------------
__global__ __launch_bounds__(256) void pol_gemm(const float* __restrict__ pb1) {
  __shared__ __align__(16) __hip_bfloat16 As[2][128 * 72];
  __shared__ __align__(16) __hip_bfloat16 Bs[2][128 * 72];
  const int tid = threadIdx.x, l = tid & 63, w = tid >> 6;
  const int bm = blockIdx.x / 8, bn = blockIdx.x % 8;
  const __hip_bfloat16* A = g_pin_all + (size_t)bm * 128 * PK;
  const __hip_bfloat16* B = g_pw1_bf  + (size_t)bn * 128 * PK;
  const int roff = (w >> 1) * 64, coff = (w & 1) * 64;

  short8 ra[4], rb[4];
#define PL_LOAD(KT) { _Pragma("unroll") for (int q = 0; q < 4; ++q) { \
    int cch = q * 256 + tid; int row = cch >> 3, ko = (cch & 7) * 8; \
    ra[q] = *(const short8*)(A + (size_t)row * PK + (KT) * 64 + ko); \
    rb[q] = *(const short8*)(B + (size_t)row * PK + (KT) * 64 + ko); } }
#define PL_STORE(BUF) { _Pragma("unroll") for (int q = 0; q < 4; ++q) { \
    int cch = q * 256 + tid; int row = cch >> 3, ko = (cch & 7) * 8; \
    *(short8*)(&As[BUF][row * 72 + ko]) = ra[q]; \
    *(short8*)(&Bs[BUF][row * 72 + ko]) = rb[q]; } }

  PL_LOAD(0); PL_STORE(0);
  f32x4 acc[4][4] = {};
  for (int kt = 0; kt < 17; ++kt) {
    __syncthreads();
    if (kt < 16) PL_LOAD(kt + 1);
    const int buf = kt & 1;
#pragma unroll
    for (int ks = 0; ks < 2; ++ks) {
      short8 a[4], b[4];
#pragma unroll
      for (int fr = 0; fr < 4; ++fr)
        a[fr] = *(const short8*)(&As[buf][(roff + fr * 16 + (l & 15)) * 72 + ks * 32 + (l >> 4) * 8]);
#pragma unroll
      for (int fc = 0; fc < 4; ++fc)
        b[fc] = *(const short8*)(&Bs[buf][(coff + fc * 16 + (l & 15)) * 72 + ks * 32 + (l >> 4) * 8]);
#pragma unroll
      for (int fr = 0; fr < 4; ++fr)
#pragma unroll
        for (int fc = 0; fc < 4; ++fc)
          acc[fr][fc] = __builtin_amdgcn_mfma_f32_16x16x32_bf16(a[fr], b[fc], acc[fr][fc], 0, 0, 0);
    }
    if (kt < 16) PL_STORE((kt + 1) & 1);
  }
#pragma unroll
  for (int fc = 0; fc < 4; ++fc) {
    int col = bn * 128 + coff + fc * 16 + (l & 15);
    float b1v = pb1[col];
#pragma unroll
    for (int fr = 0; fr < 4; ++fr)
#pragma unroll
      for (int reg = 0; reg < 4; ++reg) {
        int row = bm * 128 + roff + fr * 16 + (l >> 4) * 4 + reg;
        g_ph_all[(size_t)row * HH + col] = __float2bfloat16(tanhf_(acc[fr][fc][reg] + b1v));
      }
  }
}

// ---------------- post: pdist = ph_all @ pw2.T + b2 ----------------
__global__ __launch_bounds__(256) void pdist_kernel(const float* __restrict__ pb2,
                                                    float* __restrict__ out) {
  const int tid = threadIdx.x, l = tid & 63, w = tid >> 6;
  const int r0 = blockIdx.x * 64;
  f32x4 pa = {};
  const __hip_bfloat16* PH = g_ph_all + (size_t)(r0 + w * 16 + (l & 15)) * HH;
  const __hip_bfloat16* B  = g_pw2_bf + (size_t)(l & 15) * HH;
#pragma unroll 4
  for (int k32 = 0; k32 < 32; ++k32) {
    short8 a = *(const short8*)(PH + k32 * 32 + (l >> 4) * 8);
    short8 b = *(const short8*)(B  + k32 * 32 + (l >> 4) * 8);
    pa = __builtin_amdgcn_mfma_f32_16x16x32_bf16(a, b, pa, 0, 0, 0);
  }
  int o = l & 15;
  float bb = pb2[o];
#pragma unroll
  for (int reg = 0; reg < 4; ++reg) {
    int row = r0 + w * 16 + (l >> 4) * 4 + reg;
    out[PD_OFF + (size_t)row * AA + o] = pa[reg] + bb;
  }
}

// ---------------- final: hxs output ----------------
__global__ __launch_bounds__(256) void final_kernel(float* __restrict__ out) {
  int f = blockIdx.x * 256 + threadIdx.x;   // < 131072
  int n = f >> 11, j = f & 2047;
  out[HXS_OFF + f] = (j < HH) ? g_h[n * HH + j] : g_pol[n * HH + (j - HH)];
}

extern "C" void kernel_launch(void* const* d_in, const int* in_sizes, int n_in,
                              void* d_out, int out_size, void* d_ws, size_t ws_size,
                              hipStream_t stream) {
  const float* c     = (const float*)d_in[0];
  const float* hxs   = (const float*)d_in[1];
  const float* masks = (const float*)d_in[2];
  const float* act   = (const float*)d_in[3];
  const float* wih_h = (const float*)d_in[4];
  const float* whh_h = (const float*)d_in[5];
  const float* bih_h = (const float*)d_in[6];
  const float* bhh_h = (const float*)d_in[7];
  const float* wih_p = (const float*)d_in[8];
  const float* whh_p = (const float*)d_in[9];
  const float* bih_p = (const float*)d_in[10];
  const float* bhh_p = (const float*)d_in[11];
  const float* pw1   = (const float*)d_in[12];
  const float* pb1   = (const float*)d_in[13];
  const float* pw2   = (const float*)d_in[14];
  const float* pb2   = (const float*)d_in[15];
  float* out = (float*)d_out;

  const int wlds_bytes = 48 * WLDS_STRIDE * 2;   // 99072
  (void)hipFuncSetAttribute((const void*)step_persist,
                            hipFuncAttributeMaxDynamicSharedMemorySize, wlds_bytes);

  conv_all<<<4096, 256, 0, stream>>>(c, masks, act, wih_h, wih_p, whh_h, whh_p, pw1, pw2);
  init_kernel<<<256, 256, 0, stream>>>(hxs, masks);
  pre_gemm<<<3072, 256, 0, stream>>>();
  step_persist<<<NBLK, 256, wlds_bytes, stream>>>(masks, bih_h, bhh_h, bih_p, bhh_p, out);
  pol_gemm<<<512, 256, 0, stream>>>(pb1);
  pdist_kernel<<<128, 256, 0, stream>>>(pb2, out);
  final_kernel<<<512, 256, 0, stream>>>(out);
}

// Round 10
// 1516.575 us; speedup vs baseline: 3.1775x; 1.0084x over previous
//
#include <hip/hip_runtime.h>
#include <hip/hip_bf16.h>
#include <math.h>

#define TT 128
#define NN 64
#define HH 1024
#define AA 16
#define G3 3072          /* 3*HH */
#define NC 6144          /* combined gi cols */
#define PK 1088          /* padded policy K (1040 -> 1088 = 17*64), zero tail */
#define WLDS_STRIDE 1032 /* LDS stride for persistent weight tile */
#define NBLK 128         /* persistent grid */
#define GISL 3072        /* gi2 floats per (colblock, t): 64 rows * 48 */

#define PD_OFF  0
#define POL_OFF (TT*NN*AA)                  /* 131072 */
#define HXS_OFF (POL_OFF + TT*NN*HH)        /* 8519680 */

typedef __attribute__((ext_vector_type(8))) short short8;
typedef __attribute__((ext_vector_type(4))) float f32x4;

// ---- persistent device buffers (fully rewritten every call) ----
__device__ __align__(16) __hip_bfloat16 g_c_bf[TT*NN*HH];
__device__ __align__(16) __hip_bfloat16 g_wihc_bf[NC*HH];
__device__ __align__(16) __hip_bfloat16 g_whh_bf[2][G3*HH];
__device__ __align__(16) __hip_bfloat16 g_pw1_bf[HH*PK];
__device__ __align__(16) __hip_bfloat16 g_pw2_bf[AA*HH];
__device__ float g_gi2[(size_t)2*64*TT*GISL];                   // 201 MB, consumer-contiguous
__device__ float g_h[NN*HH];
__device__ float g_pol[NN*HH];
__device__ __align__(16) __hip_bfloat16 g_pin_all[(size_t)(TT+1)*NN*PK];  // [h(t-1)*m_t | a_t*m_t | 0]
__device__ __align__(16) __hip_bfloat16 g_polm_all[(size_t)(TT+1)*NN*HH]; // pol(t-1)*m_t, time-indexed
__device__ __align__(16) __hip_bfloat16 g_ph_all[TT*NN*HH];      // tanh(policy hidden), bf16

// packed arrival flags: 64 x u32 per GRU group = 2 cache lines per poll
__device__ __align__(256) unsigned g_flagsA[2][64];

__device__ __forceinline__ float sigmoidf_(float x) { return 1.0f / (1.0f + __expf(-x)); }
__device__ __forceinline__ float tanhf_(float x) {
  float e = __expf(2.0f * x);
  return 1.0f - 2.0f / (e + 1.0f);
}

// ---------------- conversions ----------------
__global__ __launch_bounds__(256) void conv_all(
    const float* __restrict__ c, const float* __restrict__ masks, const float* __restrict__ act,
    const float* __restrict__ wih_h, const float* __restrict__ wih_p,
    const float* __restrict__ whh_h, const float* __restrict__ whh_p,
    const float* __restrict__ pw1, const float* __restrict__ pw2)
{
  size_t i = (size_t)blockIdx.x * 256 + threadIdx.x;
  size_t stride = (size_t)gridDim.x * 256;
  for (size_t f = i; f < (size_t)TT*NN*HH; f += stride) g_c_bf[f] = __float2bfloat16(c[f]);
  for (size_t f = i; f < (size_t)G3*HH; f += stride) {
    g_wihc_bf[f]                 = __float2bfloat16(wih_h[f]);
    g_wihc_bf[(size_t)G3*HH + f] = __float2bfloat16(wih_p[f]);
    g_whh_bf[0][f] = __float2bfloat16(whh_h[f]);
    g_whh_bf[1][f] = __float2bfloat16(whh_p[f]);
  }
  for (size_t f = i; f < (size_t)HH*PK; f += stride) {
    int o = (int)(f / PK), j = (int)(f % PK);
    g_pw1_bf[f] = (j < HH + AA) ? __float2bfloat16(pw1[(size_t)o*(HH+AA) + j]) : __float2bfloat16(0.0f);
  }
  for (size_t f = i; f < (size_t)AA*HH; f += stride) g_pw2_bf[f] = __float2bfloat16(pw2[f]);
  for (size_t f = i; f < (size_t)TT*NN*(PK-HH); f += stride) {
    int row = (int)(f >> 6), j = (int)(f & 63);
    float v = (j < AA) ? act[(size_t)row*AA + j] * masks[row] : 0.0f;
    g_pin_all[(size_t)row*PK + HH + j] = __float2bfloat16(v);
  }
}

__global__ __launch_bounds__(256) void init_kernel(const float* __restrict__ hxs,
                                                   const float* __restrict__ masks) {
  int f = blockIdx.x * 256 + threadIdx.x;      // NN*HH threads
  int n = f >> 10, j = f & 1023;
  float m0 = masks[n];
  float hv = hxs[n * 2 * HH + j];
  float pv = hxs[n * 2 * HH + HH + j];
  g_h[f] = hv;
  g_pol[f] = pv;
  g_pin_all[(size_t)n * PK + j] = __float2bfloat16(hv * m0);
  g_polm_all[(size_t)n * HH + j] = __float2bfloat16(pv * m0);
  if (f < 128)
    __hip_atomic_store(&g_flagsA[f >> 6][f & 63], 0u,
                       __ATOMIC_RELAXED, __HIP_MEMORY_SCOPE_AGENT);
}

// ---------------- pre_gemm: gi = c @ [wih_h;wih_p].T   128x128 tile, BK=64, dbuf ----------------
__global__ __launch_bounds__(256) void pre_gemm() {
  __shared__ __align__(16) __hip_bfloat16 As[2][128 * 72];
  __shared__ __align__(16) __hip_bfloat16 Bs[2][128 * 72];
  const int tid = threadIdx.x, l = tid & 63, w = tid >> 6;
  const int bm = blockIdx.x / 48, bn = blockIdx.x % 48;
  const __hip_bfloat16* A = g_c_bf    + (size_t)bm * 128 * HH;
  const __hip_bfloat16* B = g_wihc_bf + (size_t)bn * 128 * HH;
  const int roff = (w >> 1) * 64, coff = (w & 1) * 64;

  short8 ra[4], rb[4];
#define PG_LOAD(KT) { _Pragma("unroll") for (int q = 0; q < 4; ++q) { \
    int cch = q * 256 + tid; int row = cch >> 3, ko = (cch & 7) * 8; \
    ra[q] = *(const short8*)(A + (size_t)row * HH + (KT) * 64 + ko); \
    rb[q] = *(const short8*)(B + (size_t)row * HH + (KT) * 64 + ko); } }
#define PG_STORE(BUF) { _Pragma("unroll") for (int q = 0; q < 4; ++q) { \
    int cch = q * 256 + tid; int row = cch >> 3, ko = (cch & 7) * 8; \
    *(short8*)(&As[BUF][row * 72 + ko]) = ra[q]; \
    *(short8*)(&Bs[BUF][row * 72 + ko]) = rb[q]; } }

  PG_LOAD(0); PG_STORE(0);
  f32x4 acc[4][4] = {};
  for (int kt = 0; kt < 16; ++kt) {
    __syncthreads();
    if (kt < 15) PG_LOAD(kt + 1);
    const int buf = kt & 1;
#pragma unroll
    for (int ks = 0; ks < 2; ++ks) {
      short8 a[4], b[4];
#pragma unroll
      for (int fr = 0; fr < 4; ++fr)
        a[fr] = *(const short8*)(&As[buf][(roff + fr * 16 + (l & 15)) * 72 + ks * 32 + (l >> 4) * 8]);
#pragma unroll
      for (int fc = 0; fc < 4; ++fc)
        b[fc] = *(const short8*)(&Bs[buf][(coff + fc * 16 + (l & 15)) * 72 + ks * 32 + (l >> 4) * 8]);
#pragma unroll
      for (int fr = 0; fr < 4; ++fr)
#pragma unroll
        for (int fc = 0; fc < 4; ++fc)
          acc[fr][fc] = __builtin_amdgcn_mfma_f32_16x16x32_bf16(a[fr], b[fc], acc[fr][fc], 0, 0, 0);
    }
    if (kt < 15) PG_STORE((kt + 1) & 1);
  }
#pragma unroll
  for (int fr = 0; fr < 4; ++fr)
#pragma unroll
    for (int fc = 0; fc < 4; ++fc) {
      int col = bn * 128 + coff + fc * 16 + (l & 15);
      int q   = col >> 10;            // gru*3 + gate
      int gru = (q >= 3), gate = q - 3 * gru;
      int hcol = col & 1023, cb = hcol >> 4, j = hcol & 15;
#pragma unroll
      for (int reg = 0; reg < 4; ++reg) {
        int grow = bm * 128 + roff + fr * 16 + (l >> 4) * 4 + reg;
        int t = grow >> 6, n = grow & 63;
        g_gi2[((size_t)(gru * 64 + cb) * TT + t) * GISL + n * 48 + gate * 16 + j] = acc[fr][fc][reg];
      }
    }
}

// ---------------- persistent 2-GRU scan kernel ----------------
// 128 blocks: 0..63 GRU-h (cols idx*16), 64..127 GRU-pol. Independent flag barrier per GRU group.
// Producers publish via relaxed sc1 stores (L3). Consumers: plain wide loads on time-indexed slabs.
// Flags packed 64 x u32 per group: poll touches 2 cache lines, not 64.
__global__ __launch_bounds__(256, 1) void step_persist(
    const float* __restrict__ masks,
    const float* __restrict__ bih_h, const float* __restrict__ bhh_h,
    const float* __restrict__ bih_p, const float* __restrict__ bhh_p,
    float* __restrict__ out)
{
  extern __shared__ __align__(16) __hip_bfloat16 Ws[];   // [48][WLDS_STRIDE]
  __shared__ float m_lds[TT * NN];                       // 32 KB masks
  __shared__ __align__(8) __hip_bfloat16 sL[NN * 16];    // 2 KB repack tile
  const int tid = threadIdx.x, l = tid & 63, w = tid >> 6;
  const int gru = blockIdx.x >> 6;
  const int idx = blockIdx.x & 63;
  const int c0  = idx * 16;
  const __hip_bfloat16* __restrict__ W = g_whh_bf[gru];

  for (int i = tid; i < TT * NN; i += 256) m_lds[i] = masks[i];

  for (int ch = tid; ch < 48 * 128; ch += 256) {
    int row = ch >> 7, ko = (ch & 127) * 8;
    int gate = row >> 4, j = row & 15;
    *(short8*)(&Ws[row * WLDS_STRIDE + ko]) =
        *(const short8*)(W + (size_t)(gate * HH + c0 + j) * HH + ko);
  }
  __syncthreads();

  const float* bi = (gru == 0) ? bih_h : bih_p;
  const float* bh = (gru == 0) ? bhh_h : bhh_p;
  const int col = c0 + (l & 15);
  const float bir = bi[col],        bhr = bh[col];
  const float biz = bi[HH + col],   bhz = bh[HH + col];
  const float bin = bi[2*HH + col], bhn = bh[2*HH + col];
  const int rowbase = w * 16 + (l >> 4) * 4;
  const int arow = w * 16 + (l & 15);
  const int lo8 = (l >> 4) * 8;
  const int jj = l & 15;

  // gates r,z weight fragments in registers (constant across all steps)
  short8 breg[64];
#pragma unroll
  for (int k32 = 0; k32 < 32; ++k32) {
    breg[k32 * 2 + 0] = *(const short8*)(&Ws[( 0 + jj) * WLDS_STRIDE + k32 * 32 + lo8]);
    breg[k32 * 2 + 1] = *(const short8*)(&Ws[(16 + jj) * WLDS_STRIDE + k32 * 32 + lo8]);
  }

  float hst[4];
  {
    const float* st0 = (gru == 0) ? g_h : g_pol;
#pragma unroll
    for (int reg = 0; reg < 4; ++reg) hst[reg] = st0[(rowbase + reg) * HH + col];
  }

  const float* __restrict__ gib = g_gi2 + (size_t)(gru * 64 + idx) * TT * GISL;
  float gir[4], giz[4], gin[4];
#pragma unroll
  for (int reg = 0; reg < 4; ++reg) {
    const float* gp = gib + (size_t)(rowbase + reg) * 48;       // t = 0
    gir[reg] = gp[jj]; giz[reg] = gp[16 + jj]; gin[reg] = gp[32 + jj];
  }

  const int astr = (gru == 0) ? PK : HH;
  volatile unsigned* __restrict__ myflags = g_flagsA[gru];

  for (int t = 0; t < TT; ++t) {
    const __hip_bfloat16* __restrict__ Ab =
        (gru == 0) ? (g_pin_all + (size_t)t * NN * PK)
                   : (g_polm_all + (size_t)t * NN * HH);
    const __hip_bfloat16* __restrict__ arowp = Ab + (size_t)arow * astr + lo8;

    // plain wide A-loads — pipelined global_load_dwordx4
    short8 av[32];
#pragma unroll
    for (int u = 0; u < 32; ++u) av[u] = *(const short8*)(arowp + u * 32);

    f32x4 acc0 = {}, acc1 = {}, acc2 = {};
#pragma unroll
    for (int u = 0; u < 32; ++u) {
      short8 bn2 = *(const short8*)(&Ws[(32 + jj) * WLDS_STRIDE + u * 32 + lo8]);
      acc0 = __builtin_amdgcn_mfma_f32_16x16x32_bf16(av[u], breg[u * 2 + 0], acc0, 0, 0, 0);
      acc1 = __builtin_amdgcn_mfma_f32_16x16x32_bf16(av[u], breg[u * 2 + 1], acc1, 0, 0, 0);
      acc2 = __builtin_amdgcn_mfma_f32_16x16x32_bf16(av[u], bn2, acc2, 0, 0, 0);
    }

    float hv_out[4];
#pragma unroll
    for (int reg = 0; reg < 4; ++reg) {
      int row = rowbase + reg;
      float mk  = m_lds[t * NN + row];
      float mk1 = (t < TT - 1) ? m_lds[(t + 1) * NN + row] : 1.0f;
      float hm = hst[reg] * mk;
      float rg  = sigmoidf_(gir[reg] + acc0[reg] + bir + bhr);
      float z   = sigmoidf_(giz[reg] + acc1[reg] + biz + bhz);
      float nn2 = tanhf_  (gin[reg] + bin + rg * (acc2[reg] + bhn));
      float hv = (1.0f - z) * nn2 + z * hm;
      hst[reg] = hv;
      hv_out[reg] = hv;
      sL[row * 16 + jj] = __float2bfloat16(hv * mk1);
    }

    __syncthreads();   // sL complete (also orders: no wave re-writes sL before all reads below)
    {
      int rr = tid >> 2, cc = tid & 3;
      unsigned long long v = *(const unsigned long long*)(&sL[rr * 16 + cc * 4]);
      __hip_bfloat16* dstp = (gru == 0)
          ? (g_pin_all + (size_t)(t + 1) * NN * PK + (size_t)rr * PK + c0 + cc * 4)
          : (g_polm_all + (size_t)(t + 1) * NN * HH + (size_t)rr * HH + c0 + cc * 4);
      __hip_atomic_store((unsigned long long*)dstp, v,
                         __ATOMIC_RELAXED, __HIP_MEMORY_SCOPE_AGENT);
    }

    if (t < TT - 1) {
      asm volatile("s_waitcnt vmcnt(0)" ::: "memory");   // publish drained to L3
      __syncthreads();                                   // all waves drained
      if (tid == 0)
        __hip_atomic_store((unsigned*)&g_flagsA[gru][idx], (unsigned)(t + 1),
                           __ATOMIC_RELAXED, __HIP_MEMORY_SCOPE_AGENT);
      // out stores + gi prefetch after flag (overlap the poll window)
      if (gru == 1) {
#pragma unroll
        for (int reg = 0; reg < 4; ++reg)
          out[POL_OFF + (size_t)(t * NN + rowbase + reg) * HH + col] = hv_out[reg];
      }
      {
        const float* gpt = gib + (size_t)(t + 1) * GISL;
#pragma unroll
        for (int reg = 0; reg < 4; ++reg) {
          const float* gp = gpt + (size_t)(rowbase + reg) * 48;
          gir[reg] = gp[jj]; giz[reg] = gp[16 + jj]; gin[reg] = gp[32 + jj];
        }
      }
      // every wave polls all 64 flags itself (lane l watches flag l): 2 cache lines total.
      // No trailing __syncthreads — each wave independently verified all producers.
      while (__hip_atomic_load((const unsigned*)&myflags[l], __ATOMIC_RELAXED,
                               __HIP_MEMORY_SCOPE_AGENT) < (unsigned)(t + 1)) { }
    } else {
      if (gru == 1) {
#pragma unroll
        for (int reg = 0; reg < 4; ++reg)
          out[POL_OFF + (size_t)(t * NN + rowbase + reg) * HH + col] = hv_out[reg];
      }
    }
  }

  float* stf = (gru == 0) ? g_h : g_pol;
#pragma unroll
  for (int reg = 0; reg < 4; ++reg) stf[(rowbase + reg) * HH + col] = hst[reg];
}

// ---------------- post: ph_all = tanh(pin_all @ pw1.T + b1)   128x128 tile ----------------
__global__ __launch_bounds__(256) void pol_gemm(const float* __restrict__ pb1) {
  __shared__ __align__(16) __hip_bfloat16 As[2][128 * 72];
  __shared__ __align__(16) __hip_bfloat16 Bs[2][128 * 72];
  const int tid = threadIdx.x, l = tid & 63, w = tid >> 6;
  const int bm = blockIdx.x / 8, bn = blockIdx.x % 8;
  const __hip_bfloat16* A = g_pin_all + (size_t)bm * 128 * PK;
  const __hip_bfloat16* B = g_pw1_bf  + (size_t)bn * 128 * PK;
  const int roff = (w >> 1) * 64, coff = (w & 1) * 64;

  short8 ra[4], rb[4];
#define PL_LOAD(KT) { _Pragma("unroll") for (int q = 0; q < 4; ++q) { \
    int cch = q * 256 + tid; int row = cch >> 3, ko = (cch & 7) * 8; \
    ra[q] = *(const short8*)(A + (size_t)row * PK + (KT) * 64 + ko); \
    rb[q] = *(const short8*)(B + (size_t)row * PK + (KT) * 64 + ko); } }
#define PL_STORE(BUF) { _Pragma("unroll") for (int q = 0; q < 4; ++q) { \
    int cch = q * 256 + tid; int row = cch >> 3, ko = (cch & 7) * 8; \
    *(short8*)(&As[BUF][row * 72 + ko]) = ra[q]; \
    *(short8*)(&Bs[BUF][row * 72 + ko]) = rb[q]; } }

  PL_LOAD(0); PL_STORE(0);
  f32x4 acc[4][4] = {};
  for (int kt = 0; kt < 17; ++kt) {
    __syncthreads();
    if (kt < 16) PL_LOAD(kt + 1);
    const int buf = kt & 1;
#pragma unroll
    for (int ks = 0; ks < 2; ++ks) {
      short8 a[4], b[4];
#pragma unroll
      for (int fr = 0; fr < 4; ++fr)
        a[fr] = *(const short8*)(&As[buf][(roff + fr * 16 + (l & 15)) * 72 + ks * 32 + (l >> 4) * 8]);
#pragma unroll
      for (int fc = 0; fc < 4; ++fc)
        b[fc] = *(const short8*)(&Bs[buf][(coff + fc * 16 + (l & 15)) * 72 + ks * 32 + (l >> 4) * 8]);
#pragma unroll
      for (int fr = 0; fr < 4; ++fr)
#pragma unroll
        for (int fc = 0; fc < 4; ++fc)
          acc[fr][fc] = __builtin_amdgcn_mfma_f32_16x16x32_bf16(a[fr], b[fc], acc[fr][fc], 0, 0, 0);
    }
    if (kt < 16) PL_STORE((kt + 1) & 1);
  }
#pragma unroll
  for (int fc = 0; fc < 4; ++fc) {
    int col = bn * 128 + coff + fc * 16 + (l & 15);
    float b1v = pb1[col];
#pragma unroll
    for (int fr = 0; fr < 4; ++fr)
#pragma unroll
      for (int reg = 0; reg < 4; ++reg) {
        int row = bm * 128 + roff + fr * 16 + (l >> 4) * 4 + reg;
        g_ph_all[(size_t)row * HH + col] = __float2bfloat16(tanhf_(acc[fr][fc][reg] + b1v));
      }
  }
}

// ---------------- post: pdist = ph_all @ pw2.T + b2 ----------------
__global__ __launch_bounds__(256) void pdist_kernel(const float* __restrict__ pb2,
                                                    float* __restrict__ out) {
  const int tid = threadIdx.x, l = tid & 63, w = tid >> 6;
  const int r0 = blockIdx.x * 64;
  f32x4 pa = {};
  const __hip_bfloat16* PH = g_ph_all + (size_t)(r0 + w * 16 + (l & 15)) * HH;
  const __hip_bfloat16* B  = g_pw2_bf + (size_t)(l & 15) * HH;
#pragma unroll 4
  for (int k32 = 0; k32 < 32; ++k32) {
    short8 a = *(const short8*)(PH + k32 * 32 + (l >> 4) * 8);
    short8 b = *(const short8*)(B  + k32 * 32 + (l >> 4) * 8);
    pa = __builtin_amdgcn_mfma_f32_16x16x32_bf16(a, b, pa, 0, 0, 0);
  }
  int o = l & 15;
  float bb = pb2[o];
#pragma unroll
  for (int reg = 0; reg < 4; ++reg) {
    int row = r0 + w * 16 + (l >> 4) * 4 + reg;
    out[PD_OFF + (size_t)row * AA + o] = pa[reg] + bb;
  }
}

// ---------------- final: hxs output ----------------
__global__ __launch_bounds__(256) void final_kernel(float* __restrict__ out) {
  int f = blockIdx.x * 256 + threadIdx.x;   // < 131072
  int n = f >> 11, j = f & 2047;
  out[HXS_OFF + f] = (j < HH) ? g_h[n * HH + j] : g_pol[n * HH + (j - HH)];
}

extern "C" void kernel_launch(void* const* d_in, const int* in_sizes, int n_in,
                              void* d_out, int out_size, void* d_ws, size_t ws_size,
                              hipStream_t stream) {
  const float* c     = (const float*)d_in[0];
  const float* hxs   = (const float*)d_in[1];
  const float* masks = (const float*)d_in[2];
  const float* act   = (const float*)d_in[3];
  const float* wih_h = (const float*)d_in[4];
  const float* whh_h = (const float*)d_in[5];
  const float* bih_h = (const float*)d_in[6];
  const float* bhh_h = (const float*)d_in[7];
  const float* wih_p = (const float*)d_in[8];
  const float* whh_p = (const float*)d_in[9];
  const float* bih_p = (const float*)d_in[10];
  const float* bhh_p = (const float*)d_in[11];
  const float* pw1   = (const float*)d_in[12];
  const float* pb1   = (const float*)d_in[13];
  const float* pw2   = (const float*)d_in[14];
  const float* pb2   = (const float*)d_in[15];
  float* out = (float*)d_out;

  const int wlds_bytes = 48 * WLDS_STRIDE * 2;   // 99072
  (void)hipFuncSetAttribute((const void*)step_persist,
                            hipFuncAttributeMaxDynamicSharedMemorySize, wlds_bytes);

  conv_all<<<4096, 256, 0, stream>>>(c, masks, act, wih_h, wih_p, whh_h, whh_p, pw1, pw2);
  init_kernel<<<256, 256, 0, stream>>>(hxs, masks);
  pre_gemm<<<3072, 256, 0, stream>>>();
  step_persist<<<NBLK, 256, wlds_bytes, stream>>>(masks, bih_h, bhh_h, bih_p, bhh_p, out);
  pol_gemm<<<512, 256, 0, stream>>>(pb1);
  pdist_kernel<<<128, 256, 0, stream>>>(pb2, out);
  final_kernel<<<512, 256, 0, stream>>>(out);
}